// Round 1
// baseline (825.915 us; speedup 1.0000x reference)
//
#include <hip/hip_runtime.h>
#include <hip/hip_bf16.h>

#define S_LEN   2048
#define HID     1024
#define NH      16
#define HD      64
#define WIN     512
#define NW      4
#define NG      64
#define GSTRIDE 32
#define SCALE   0.125f   // 64^-0.5

// ---------------- GEMM: C[M][N] = A[M][K] @ B[N][K]^T + bias[N] ----------------
// Both A and B are row-major with K contiguous (B used transposed), so all
// global loads are float4-coalesced. Tile 128x64, BK=16, 256 thr, 8x4/thread.
#define TM 128
#define TN 64
#define BK 16

__global__ __launch_bounds__(256) void gemm_bias_kernel(
    const float* __restrict__ A, const float* __restrict__ B,
    const float* __restrict__ bias, float* __restrict__ C,
    int M, int N, int K)
{
    // LDS stored k-major (As[k][m]) so compute reads are contiguous -> ds_read_b128
    __shared__ float As[BK][TM + 4];
    __shared__ float Bs[BK][TN + 4];
    const int tid = threadIdx.x;
    const int bm = blockIdx.y * TM;
    const int bn = blockIdx.x * TN;
    const int tx = tid & 15;   // 16 col-groups of 4
    const int ty = tid >> 4;   // 16 row-groups of 8

    float acc[8][4];
#pragma unroll
    for (int i = 0; i < 8; ++i)
#pragma unroll
        for (int j = 0; j < 4; ++j) acc[i][j] = 0.f;

    for (int k0 = 0; k0 < K; k0 += BK) {
        __syncthreads();
        // A tile: 128 rows x 16 k = 512 float4, 2/thread
#pragma unroll
        for (int t = 0; t < 2; ++t) {
            int f = tid + t * 256;
            int row = f >> 2, kq = f & 3;
            float4 va = *(const float4*)&A[(size_t)(bm + row) * K + k0 + kq * 4];
            As[kq * 4 + 0][row] = va.x; As[kq * 4 + 1][row] = va.y;
            As[kq * 4 + 2][row] = va.z; As[kq * 4 + 3][row] = va.w;
        }
        // B tile: 64 rows x 16 k = 256 float4, 1/thread
        {
            int row = tid >> 2, kq = tid & 3;
            float4 vb = *(const float4*)&B[(size_t)(bn + row) * K + k0 + kq * 4];
            Bs[kq * 4 + 0][row] = vb.x; Bs[kq * 4 + 1][row] = vb.y;
            Bs[kq * 4 + 2][row] = vb.z; Bs[kq * 4 + 3][row] = vb.w;
        }
        __syncthreads();
#pragma unroll
        for (int kk = 0; kk < BK; ++kk) {
            float a[8], b[4];
#pragma unroll
            for (int i = 0; i < 8; ++i) a[i] = As[kk][ty * 8 + i];
#pragma unroll
            for (int j = 0; j < 4; ++j) b[j] = Bs[kk][tx * 4 + j];
#pragma unroll
            for (int i = 0; i < 8; ++i)
#pragma unroll
                for (int j = 0; j < 4; ++j)
                    acc[i][j] = fmaf(a[i], b[j], acc[i][j]);
        }
    }
#pragma unroll
    for (int i = 0; i < 8; ++i) {
        int row = bm + ty * 8 + i;
#pragma unroll
        for (int j = 0; j < 4; ++j) {
            int col = bn + tx * 4 + j;
            C[(size_t)row * N + col] = acc[i][j] + bias[col];
        }
    }
}

// ---------------- per-window / global V sums (for the zero-score correction) ----
__global__ __launch_bounds__(64) void vsum_kernel(const float* __restrict__ v,
    float* __restrict__ vwin, float* __restrict__ vgwin)
{
    int n = blockIdx.x, h = blockIdx.y, d = threadIdx.x;
    float s = 0.f, sg = 0.f;
    for (int j = 0; j < WIN; ++j) {
        float val = v[(size_t)(n * WIN + j) * HID + h * HD + d];
        s += val;
        if ((j & (GSTRIDE - 1)) == 0) sg += val;
    }
    vwin[(n * NH + h) * HD + d] = s;
    vgwin[(n * NH + h) * HD + d] = sg;
}

// vrest_ng[n][h][d] = sum of v over NON-attended keys for a non-global query in window n
// vrest_g [n][h][d] = same for a global query (also attends out-of-window global keys)
__global__ __launch_bounds__(64) void vrest_kernel(
    const float* __restrict__ vwin, const float* __restrict__ vgwin,
    float* __restrict__ vrest_ng, float* __restrict__ vrest_g)
{
    int n = blockIdx.x, h = blockIdx.y, d = threadIdx.x;
    float vall = 0.f, vgall = 0.f;
    for (int n2 = 0; n2 < NW; ++n2) {
        vall += vwin[(n2 * NH + h) * HD + d];
        vgall += vgwin[(n2 * NH + h) * HD + d];
    }
    float w  = vwin[(n * NH + h) * HD + d];
    float gw = vgwin[(n * NH + h) * HD + d];
    vrest_ng[(n * NH + h) * HD + d] = vall - w;
    vrest_g[(n * NH + h) * HD + d]  = vall - w - (vgall - gw);
}

// ---------------- attention ----------------
// Grid (8 qtiles, 16 heads, 4 windows), 128 threads = 2 waves.
// Each thread owns one query (ql = tid&63); the two waves split the 512 window
// keys (wave h takes keys [c*128 + h*64, +64) of each 128-key LDS chunk), then
// merge (l, acc) through LDS. Scores are provably tiny (|s| < ~4) so we use
// softmax shift m=0; the 2048-|attended| zero-score keys are folded in closed
// form via the precomputed vrest tables.
__global__ __launch_bounds__(128) void attn_kernel(
    const float* __restrict__ q, const float* __restrict__ k,
    const float* __restrict__ v, const float* __restrict__ vrest_ng,
    const float* __restrict__ vrest_g, float* __restrict__ att)
{
    __shared__ float smem[16384];  // K chunk [128][64] @0, V chunk @8192; merge reuses @0
    const int tid  = threadIdx.x;
    const int ql   = tid & 63;
    const int half = tid >> 6;
    const int tile = blockIdx.x;   // 0..7
    const int h    = blockIdx.y;
    const int n    = blockIdx.z;
    const int qi   = n * WIN + tile * 64 + ql;
    const bool is_glob = ((qi & (GSTRIDE - 1)) == 0);

    float qreg[HD];
#pragma unroll
    for (int d4 = 0; d4 < HD / 4; ++d4) {
        float4 t = *(const float4*)&q[(size_t)qi * HID + h * HD + d4 * 4];
        qreg[d4 * 4 + 0] = t.x; qreg[d4 * 4 + 1] = t.y;
        qreg[d4 * 4 + 2] = t.z; qreg[d4 * 4 + 3] = t.w;
    }

    float l = 0.f;
    float acc[HD];
#pragma unroll
    for (int d = 0; d < HD; ++d) acc[d] = 0.f;

    for (int c = 0; c < 4; ++c) {
        __syncthreads();
        // stage 128 keys of K and V: 2048 float4 each side, 16/thread
#pragma unroll 4
        for (int t = 0; t < 16; ++t) {
            int f = tid + t * 128;
            int key = f >> 4, d4 = f & 15;
            size_t src = (size_t)(n * WIN + c * 128 + key) * HID + h * HD + d4 * 4;
            *(float4*)&smem[key * HD + d4 * 4]        = *(const float4*)&k[src];
            *(float4*)&smem[8192 + key * HD + d4 * 4] = *(const float4*)&v[src];
        }
        __syncthreads();
        const int kofs = half * 64;
#pragma unroll 2
        for (int kk = 0; kk < 64; ++kk) {
            const float* krow = &smem[(kofs + kk) * HD];   // wave-uniform -> LDS broadcast
            float s0 = 0.f, s1 = 0.f, s2 = 0.f, s3 = 0.f;
#pragma unroll
            for (int d = 0; d < HD; d += 4) {
                s0 = fmaf(qreg[d + 0], krow[d + 0], s0);
                s1 = fmaf(qreg[d + 1], krow[d + 1], s1);
                s2 = fmaf(qreg[d + 2], krow[d + 2], s2);
                s3 = fmaf(qreg[d + 3], krow[d + 3], s3);
            }
            float s = ((s0 + s1) + (s2 + s3)) * SCALE;
            int j = n * WIN + c * 128 + kofs + kk;
            // global query + global key in same window: local + identical global dot = 2x
            if (is_glob && ((j & (GSTRIDE - 1)) == 0)) s += s;
            float p = __expf(s);
            l += p;
            const float* vrow = &smem[8192 + (kofs + kk) * HD];
#pragma unroll
            for (int d = 0; d < HD; ++d) acc[d] = fmaf(p, vrow[d], acc[d]);
        }
    }

    // out-of-window global keys (only 2 lanes/wave active; K/V hot in L2)
    if (is_glob) {
        for (int g = half; g < NG; g += 2) {
            int j = g * GSTRIDE;
            if (j >= n * WIN && j < n * WIN + WIN) continue;
            float s0 = 0.f, s1 = 0.f, s2 = 0.f, s3 = 0.f;
#pragma unroll
            for (int d4 = 0; d4 < 16; ++d4) {
                float4 kv = *(const float4*)&k[(size_t)j * HID + h * HD + d4 * 4];
                s0 = fmaf(qreg[d4 * 4 + 0], kv.x, s0);
                s1 = fmaf(qreg[d4 * 4 + 1], kv.y, s1);
                s2 = fmaf(qreg[d4 * 4 + 2], kv.z, s2);
                s3 = fmaf(qreg[d4 * 4 + 3], kv.w, s3);
            }
            float p = __expf(((s0 + s1) + (s2 + s3)) * SCALE);
            l += p;
#pragma unroll
            for (int d4 = 0; d4 < 16; ++d4) {
                float4 vv = *(const float4*)&v[(size_t)j * HID + h * HD + d4 * 4];
                acc[d4 * 4 + 0] = fmaf(p, vv.x, acc[d4 * 4 + 0]);
                acc[d4 * 4 + 1] = fmaf(p, vv.y, acc[d4 * 4 + 1]);
                acc[d4 * 4 + 2] = fmaf(p, vv.z, acc[d4 * 4 + 2]);
                acc[d4 * 4 + 3] = fmaf(p, vv.w, acc[d4 * 4 + 3]);
            }
        }
    }

    // merge the two halves (plain sums since shift m=0 everywhere)
    __syncthreads();
    if (half == 1) {
        smem[64 * 65 + ql] = l;
#pragma unroll
        for (int d = 0; d < HD; ++d) smem[ql * 65 + d] = acc[d];  // stride 65: no conflicts
    }
    __syncthreads();
    if (half == 0) {
        l += smem[64 * 65 + ql];
#pragma unroll
        for (int d = 0; d < HD; ++d) acc[d] += smem[ql * 65 + d];
        const int n_att = WIN + (is_glob ? (NG - WIN / GSTRIDE) : 0);  // 512 or 560
        l += (float)(S_LEN - n_att);                 // exp(0)=1 per non-attended key
        const float* vr = (is_glob ? vrest_g : vrest_ng) + (size_t)(n * NH + h) * HD;
#pragma unroll
        for (int d = 0; d < HD; ++d) acc[d] += vr[d];
        float invl = 1.f / l;
#pragma unroll
        for (int d4 = 0; d4 < 16; ++d4) {
            float4 o;
            o.x = acc[d4 * 4 + 0] * invl; o.y = acc[d4 * 4 + 1] * invl;
            o.z = acc[d4 * 4 + 2] * invl; o.w = acc[d4 * 4 + 3] * invl;
            *(float4*)&att[(size_t)qi * HID + h * HD + d4 * 4] = o;
        }
    }
}

extern "C" void kernel_launch(void* const* d_in, const int* in_sizes, int n_in,
                              void* d_out, int out_size, void* d_ws, size_t ws_size,
                              hipStream_t stream) {
    const float* x  = (const float*)d_in[0];
    const float* wq = (const float*)d_in[1];
    const float* bq = (const float*)d_in[2];
    const float* wk = (const float*)d_in[3];
    const float* bk = (const float*)d_in[4];
    const float* wv = (const float*)d_in[5];
    const float* bv = (const float*)d_in[6];
    const float* wo = (const float*)d_in[7];
    const float* bo = (const float*)d_in[8];
    float* out = (float*)d_out;

    float* ws = (float*)d_ws;
    float* q        = ws;                       // 2M floats
    float* k        = ws + 2u * 1024 * 1024;    // 2M
    float* v        = ws + 4u * 1024 * 1024;    // 2M
    float* att      = ws + 6u * 1024 * 1024;    // 2M
    float* vwin     = ws + 8u * 1024 * 1024;    // 4096
    float* vgwin    = vwin + NW * NH * HD;      // 4096
    float* vrest_ng = vgwin + NW * NH * HD;     // 4096
    float* vrest_g  = vrest_ng + NW * NH * HD;  // 4096

    dim3 ggrid(HID / TN, S_LEN / TM);  // (16,16) = 256 blocks
    gemm_bias_kernel<<<ggrid, 256, 0, stream>>>(x, wq, bq, q, S_LEN, HID, HID);
    gemm_bias_kernel<<<ggrid, 256, 0, stream>>>(x, wk, bk, k, S_LEN, HID, HID);
    gemm_bias_kernel<<<ggrid, 256, 0, stream>>>(x, wv, bv, v, S_LEN, HID, HID);
    vsum_kernel<<<dim3(NW, NH), 64, 0, stream>>>(v, vwin, vgwin);
    vrest_kernel<<<dim3(NW, NH), 64, 0, stream>>>(vwin, vgwin, vrest_ng, vrest_g);
    attn_kernel<<<dim3(8, NH, NW), 128, 0, stream>>>(q, k, v, vrest_ng, vrest_g, att);
    gemm_bias_kernel<<<ggrid, 256, 0, stream>>>(att, wo, bo, out, S_LEN, HID, HID);
}

// Round 2
// 548.412 us; speedup vs baseline: 1.5060x; 1.5060x over previous
//
#include <hip/hip_runtime.h>
#include <hip/hip_bf16.h>

#define S_LEN   2048
#define HID     1024
#define NH      16
#define HD      64
#define WIN     512
#define NW      4
#define NG      64
#define GSTRIDE 32
#define SCALE   0.125f   // 64^-0.5

typedef __bf16 bf16x8 __attribute__((ext_vector_type(8)));
typedef float  f32x4  __attribute__((ext_vector_type(4)));
typedef unsigned short ushort_t;

// ---------------- fp32 -> bf16 hi/lo split helpers ----------------
__device__ __forceinline__ ushort_t f32_to_bf16_rne(float f) {
    unsigned int u = __float_as_uint(f);
    u = u + 0x7FFFu + ((u >> 16) & 1u);
    return (ushort_t)(u >> 16);
}
__device__ __forceinline__ float bf16_to_f32(ushort_t h) {
    return __uint_as_float(((unsigned int)h) << 16);
}

__global__ __launch_bounds__(256) void split_kernel(
    const float* __restrict__ in, ushort_t* __restrict__ hi,
    ushort_t* __restrict__ lo, int n4)
{
    int i = blockIdx.x * 256 + threadIdx.x;
    if (i >= n4) return;
    float4 f = ((const float4*)in)[i];
    ushort4 h, l;
    h.x = f32_to_bf16_rne(f.x); l.x = f32_to_bf16_rne(f.x - bf16_to_f32(h.x));
    h.y = f32_to_bf16_rne(f.y); l.y = f32_to_bf16_rne(f.y - bf16_to_f32(h.y));
    h.z = f32_to_bf16_rne(f.z); l.z = f32_to_bf16_rne(f.z - bf16_to_f32(h.z));
    h.w = f32_to_bf16_rne(f.w); l.w = f32_to_bf16_rne(f.w - bf16_to_f32(h.w));
    ((ushort4*)hi)[i] = h;
    ((ushort4*)lo)[i] = l;
}

// ---------------- async global -> LDS (16B per lane) ----------------
__device__ __forceinline__ void async16(const ushort_t* g, ushort_t* l) {
    __builtin_amdgcn_global_load_lds(
        (const __attribute__((address_space(1))) void*)g,
        (__attribute__((address_space(3))) void*)l, 16, 0, 0);
}

// ---------------- split-bf16 MFMA GEMM ----------------
// C[M][1024] = A[M][K] @ W[1024][K]^T + bias, per segment (up to 3 segments
// for fused QKV). Tile BM x 64, BK=32, 256 thr = 4 waves arranged 2x2,
// wave tile (BM/2) x 32, frags FI x 2 of 16x16x32.
// acc += Ahi*Bhi + Ahi*Blo + Alo*Bhi (split-bf16, ~1e-4 abs accuracy).
template <int BM>
__global__ __launch_bounds__(256) void gemm_mfma_kernel(
    const ushort_t* __restrict__ Ahi, const ushort_t* __restrict__ Alo,
    const ushort_t* __restrict__ Bhi0, const ushort_t* __restrict__ Blo0,
    const float* __restrict__ bias0, float* __restrict__ C0,
    const ushort_t* __restrict__ Bhi1, const ushort_t* __restrict__ Blo1,
    const float* __restrict__ bias1, float* __restrict__ C1,
    const ushort_t* __restrict__ Bhi2, const ushort_t* __restrict__ Blo2,
    const float* __restrict__ bias2, float* __restrict__ C2,
    int K)
{
    constexpr int BK = 32;
    constexpr int FI = BM / 32;      // m-frags per wave
    __shared__ ushort_t sAhi[BM * BK];
    __shared__ ushort_t sAlo[BM * BK];
    __shared__ ushort_t sBhi[64 * BK];
    __shared__ ushort_t sBlo[64 * BK];

    const int tid  = threadIdx.x;
    const int lane = tid & 63;
    const int wv   = tid >> 6;
    const int wr   = wv >> 1, wc = wv & 1;
    const int quad = lane >> 4, lm = lane & 15;
    const int seg  = blockIdx.x >> 4;             // 0..2 (fused QKV) or 0
    const int bn   = (blockIdx.x & 15) * 64;      // col base within segment
    const int bm   = blockIdx.y * BM;

    const ushort_t* Bhi = (seg == 0) ? Bhi0 : (seg == 1) ? Bhi1 : Bhi2;
    const ushort_t* Blo = (seg == 0) ? Blo0 : (seg == 1) ? Blo1 : Blo2;
    const float*   bias = (seg == 0) ? bias0 : (seg == 1) ? bias1 : bias2;
    float*            C = (seg == 0) ? C0 : (seg == 1) ? C1 : C2;

    f32x4 acc[FI][2];
#pragma unroll
    for (int i = 0; i < FI; ++i)
#pragma unroll
        for (int j = 0; j < 2; ++j) acc[i][j] = {0.f, 0.f, 0.f, 0.f};

    for (int k0 = 0; k0 < K; k0 += BK) {
        __syncthreads();
        // A tiles: BM rows x 32 k, hi+lo; 16B chunks in lane order
#pragma unroll
        for (int t = 0; t < BM / 64; ++t) {
            int c = tid + t * 256;
            int row = c >> 2, kp = c & 3;
            size_t go = (size_t)(bm + row) * K + k0 + kp * 8;
            async16(&Ahi[go], &sAhi[c * 8]);
            async16(&Alo[go], &sAlo[c * 8]);
        }
        // B tile: 64 rows x 32 k, hi+lo
        {
            int row = tid >> 2, kp = tid & 3;
            size_t go = (size_t)(bn + row) * K + k0 + kp * 8;
            async16(&Bhi[go], &sBhi[tid * 8]);
            async16(&Blo[go], &sBlo[tid * 8]);
        }
        asm volatile("s_waitcnt vmcnt(0)" ::: "memory");
        __syncthreads();

        bf16x8 afh[FI], afl[FI], bfh[2], bfl[2];
#pragma unroll
        for (int i = 0; i < FI; ++i) {
            int row = wr * (BM / 2) + i * 16 + lm;
            afh[i] = *(const bf16x8*)&sAhi[row * BK + quad * 8];
            afl[i] = *(const bf16x8*)&sAlo[row * BK + quad * 8];
        }
#pragma unroll
        for (int j = 0; j < 2; ++j) {
            int row = wc * 32 + j * 16 + lm;
            bfh[j] = *(const bf16x8*)&sBhi[row * BK + quad * 8];
            bfl[j] = *(const bf16x8*)&sBlo[row * BK + quad * 8];
        }
#pragma unroll
        for (int i = 0; i < FI; ++i)
#pragma unroll
            for (int j = 0; j < 2; ++j) {
                acc[i][j] = __builtin_amdgcn_mfma_f32_16x16x32_bf16(afh[i], bfh[j], acc[i][j], 0, 0, 0);
                acc[i][j] = __builtin_amdgcn_mfma_f32_16x16x32_bf16(afh[i], bfl[j], acc[i][j], 0, 0, 0);
                acc[i][j] = __builtin_amdgcn_mfma_f32_16x16x32_bf16(afl[i], bfh[j], acc[i][j], 0, 0, 0);
            }
    }

    // epilogue: C/D layout col=lane&15, row=quad*4+reg
#pragma unroll
    for (int i = 0; i < FI; ++i)
#pragma unroll
        for (int j = 0; j < 2; ++j) {
            int col = bn + wc * 32 + j * 16 + lm;
            float b = bias[col];
#pragma unroll
            for (int r = 0; r < 4; ++r) {
                int row = bm + wr * (BM / 2) + i * 16 + quad * 4 + r;
                C[(size_t)row * 1024 + col] = acc[i][j][r] + b;
            }
        }
}

// ---------------- per-window / global V sums (zero-score correction) ----
__global__ __launch_bounds__(64) void vsum_kernel(const float* __restrict__ v,
    float* __restrict__ vwin, float* __restrict__ vgwin)
{
    int n = blockIdx.x, h = blockIdx.y, d = threadIdx.x;
    float s = 0.f, sg = 0.f;
    for (int j = 0; j < WIN; ++j) {
        float val = v[(size_t)(n * WIN + j) * HID + h * HD + d];
        s += val;
        if ((j & (GSTRIDE - 1)) == 0) sg += val;
    }
    vwin[(n * NH + h) * HD + d] = s;
    vgwin[(n * NH + h) * HD + d] = sg;
}

__global__ __launch_bounds__(64) void vrest_kernel(
    const float* __restrict__ vwin, const float* __restrict__ vgwin,
    float* __restrict__ vrest_ng, float* __restrict__ vrest_g)
{
    int n = blockIdx.x, h = blockIdx.y, d = threadIdx.x;
    float vall = 0.f, vgall = 0.f;
    for (int n2 = 0; n2 < NW; ++n2) {
        vall += vwin[(n2 * NH + h) * HD + d];
        vgall += vgwin[(n2 * NH + h) * HD + d];
    }
    float w  = vwin[(n * NH + h) * HD + d];
    float gw = vgwin[(n * NH + h) * HD + d];
    vrest_ng[(n * NH + h) * HD + d] = vall - w;
    vrest_g[(n * NH + h) * HD + d]  = vall - w - (vgall - gw);
}

// ---------------- attention ----------------
// Grid (16 qtiles of 32, 16 heads, 4 windows) = 1024 blocks, 128 thr = 2 waves.
// Thread: query ql = tid&31, key-segment seg = tid>>5 (4 segments of 128 keys).
// 64-key K/V chunks staged in 32 KB LDS; merge: shfl within wave, LDS across.
__global__ __launch_bounds__(128) void attn_kernel(
    const float* __restrict__ q, const float* __restrict__ k,
    const float* __restrict__ v, const float* __restrict__ vrest_ng,
    const float* __restrict__ vrest_g, float* __restrict__ att)
{
    __shared__ float smem[8192];           // sk @0 [64][64], sv @4096; merge overlays @0
    float* sk = smem;
    float* sv = smem + 4096;
    const int tid  = threadIdx.x;
    const int ql   = tid & 31;
    const int seg  = tid >> 5;             // 0..3
    const int tile = blockIdx.x;           // 0..15
    const int h    = blockIdx.y;
    const int n    = blockIdx.z;
    const int qi   = n * WIN + tile * 32 + ql;
    const bool is_glob = ((qi & (GSTRIDE - 1)) == 0);

    float qreg[HD];
#pragma unroll
    for (int d4 = 0; d4 < 16; ++d4) {
        float4 t = *(const float4*)&q[(size_t)qi * HID + h * HD + d4 * 4];
        qreg[d4 * 4 + 0] = t.x; qreg[d4 * 4 + 1] = t.y;
        qreg[d4 * 4 + 2] = t.z; qreg[d4 * 4 + 3] = t.w;
    }

    float l = 0.f;
    float acc[HD];
#pragma unroll
    for (int d = 0; d < HD; ++d) acc[d] = 0.f;

    for (int c = 0; c < 8; ++c) {
        __syncthreads();
        // stage 64 keys of K and V: 1024 float4 each, 8/thread each
#pragma unroll
        for (int t = 0; t < 8; ++t) {
            int f = tid + t * 128;
            int key = f >> 4, d4 = f & 15;
            size_t src = (size_t)(n * WIN + c * 64 + key) * HID + h * HD + d4 * 4;
            *(float4*)&sk[key * HD + d4 * 4] = *(const float4*)&k[src];
            *(float4*)&sv[key * HD + d4 * 4] = *(const float4*)&v[src];
        }
        __syncthreads();
#pragma unroll 2
        for (int kk = 0; kk < 16; ++kk) {
            const int key = seg * 16 + kk;
            const float* krow = &sk[key * HD];   // uniform per 32-lane half
            float s0 = 0.f, s1 = 0.f, s2 = 0.f, s3 = 0.f;
#pragma unroll
            for (int d = 0; d < HD; d += 4) {
                s0 = fmaf(qreg[d + 0], krow[d + 0], s0);
                s1 = fmaf(qreg[d + 1], krow[d + 1], s1);
                s2 = fmaf(qreg[d + 2], krow[d + 2], s2);
                s3 = fmaf(qreg[d + 3], krow[d + 3], s3);
            }
            float s = ((s0 + s1) + (s2 + s3)) * SCALE;
            int j = n * WIN + c * 64 + key;
            if (is_glob && ((j & (GSTRIDE - 1)) == 0)) s += s;  // in-window global pair: 2x
            float p = __expf(s);
            l += p;
            const float* vrow = &sv[key * HD];
#pragma unroll
            for (int d = 0; d < HD; ++d) acc[d] = fmaf(p, vrow[d], acc[d]);
        }
    }

    // out-of-window global keys (1 global query per block; L2-hot)
    if (is_glob) {
        for (int g = seg; g < NG; g += 4) {
            int j = g * GSTRIDE;
            if (j >= n * WIN && j < n * WIN + WIN) continue;
            float s0 = 0.f, s1 = 0.f, s2 = 0.f, s3 = 0.f;
#pragma unroll
            for (int d4 = 0; d4 < 16; ++d4) {
                float4 kv = *(const float4*)&k[(size_t)j * HID + h * HD + d4 * 4];
                s0 = fmaf(qreg[d4 * 4 + 0], kv.x, s0);
                s1 = fmaf(qreg[d4 * 4 + 1], kv.y, s1);
                s2 = fmaf(qreg[d4 * 4 + 2], kv.z, s2);
                s3 = fmaf(qreg[d4 * 4 + 3], kv.w, s3);
            }
            float p = __expf(((s0 + s1) + (s2 + s3)) * SCALE);
            l += p;
#pragma unroll
            for (int d4 = 0; d4 < 16; ++d4) {
                float4 vv = *(const float4*)&v[(size_t)j * HID + h * HD + d4 * 4];
                acc[d4 * 4 + 0] = fmaf(p, vv.x, acc[d4 * 4 + 0]);
                acc[d4 * 4 + 1] = fmaf(p, vv.y, acc[d4 * 4 + 1]);
                acc[d4 * 4 + 2] = fmaf(p, vv.z, acc[d4 * 4 + 2]);
                acc[d4 * 4 + 3] = fmaf(p, vv.w, acc[d4 * 4 + 3]);
            }
        }
    }

    // merge: segs {0,1} and {2,3} within each wave via shfl (lanes 0..31 valid)
    l += __shfl_down(l, 32);
#pragma unroll
    for (int d = 0; d < HD; ++d) acc[d] += __shfl_down(acc[d], 32);

    __syncthreads();
    if (tid >= 64 && tid < 96) {           // wave1 merged half -> LDS (stride 66)
        smem[ql * 66 + 64] = l;
#pragma unroll
        for (int d = 0; d < HD; ++d) smem[ql * 66 + d] = acc[d];
    }
    __syncthreads();
    if (tid < 32) {
        l += smem[ql * 66 + 64];
#pragma unroll
        for (int d = 0; d < HD; ++d) acc[d] += smem[ql * 66 + d];
        const int n_att = WIN + (is_glob ? (NG - WIN / GSTRIDE) : 0);  // 512 or 560
        l += (float)(S_LEN - n_att);       // exp(0)=1 per non-attended key
        const float* vr = (is_glob ? vrest_g : vrest_ng) + (size_t)(n * NH + h) * HD;
#pragma unroll
        for (int d = 0; d < HD; ++d) acc[d] += vr[d];
        float invl = 1.f / l;
#pragma unroll
        for (int d4 = 0; d4 < 16; ++d4) {
            float4 o;
            o.x = acc[d4 * 4 + 0] * invl; o.y = acc[d4 * 4 + 1] * invl;
            o.z = acc[d4 * 4 + 2] * invl; o.w = acc[d4 * 4 + 3] * invl;
            *(float4*)&att[(size_t)qi * HID + h * HD + d4 * 4] = o;
        }
    }
}

extern "C" void kernel_launch(void* const* d_in, const int* in_sizes, int n_in,
                              void* d_out, int out_size, void* d_ws, size_t ws_size,
                              hipStream_t stream) {
    const float* x   = (const float*)d_in[0];
    const float* wq  = (const float*)d_in[1];
    const float* bq  = (const float*)d_in[2];
    const float* wk  = (const float*)d_in[3];
    const float* bk_ = (const float*)d_in[4];
    const float* wv  = (const float*)d_in[5];
    const float* bv  = (const float*)d_in[6];
    const float* wo  = (const float*)d_in[7];
    const float* bo  = (const float*)d_in[8];
    float* out = (float*)d_out;

    const size_t M2 = 2u * 1024 * 1024, M1 = 1024 * 1024;
    float* ws = (float*)d_ws;
    float* qbuf     = ws;
    float* kbuf     = ws + M2;
    float* vbuf     = ws + 2 * M2;
    float* attbuf   = ws + 3 * M2;
    float* vwin     = ws + 4 * M2;
    float* vgwin    = vwin + NW * NH * HD;
    float* vrest_ng = vgwin + NW * NH * HD;
    float* vrest_g  = vrest_ng + NW * NH * HD;
    ushort_t* us = (ushort_t*)(ws + 4 * M2 + 16384);
    ushort_t* xhi = us;            ushort_t* xlo = xhi + M2;
    ushort_t* wqh = xlo + M2;      ushort_t* wql = wqh + M1;
    ushort_t* wkh = wql + M1;      ushort_t* wkl = wkh + M1;
    ushort_t* wvh = wkl + M1;      ushort_t* wvl = wvh + M1;
    ushort_t* woh = wvl + M1;      ushort_t* wol = woh + M1;
    ushort_t* ath = wol + M1;      ushort_t* atl = ath + M2;

    split_kernel<<<2048, 256, 0, stream>>>(x,  xhi, xlo, (int)(M2 / 4));
    split_kernel<<<1024, 256, 0, stream>>>(wq, wqh, wql, (int)(M1 / 4));
    split_kernel<<<1024, 256, 0, stream>>>(wk, wkh, wkl, (int)(M1 / 4));
    split_kernel<<<1024, 256, 0, stream>>>(wv, wvh, wvl, (int)(M1 / 4));
    split_kernel<<<1024, 256, 0, stream>>>(wo, woh, wol, (int)(M1 / 4));

    // fused QKV: N = 3x1024, grid 48x16 = 768 blocks (3/CU)
    gemm_mfma_kernel<128><<<dim3(48, 16), 256, 0, stream>>>(
        xhi, xlo,
        wqh, wql, bq,  qbuf,
        wkh, wkl, bk_, kbuf,
        wvh, wvl, bv,  vbuf, HID);

    vsum_kernel<<<dim3(NW, NH), 64, 0, stream>>>(vbuf, vwin, vgwin);
    vrest_kernel<<<dim3(NW, NH), 64, 0, stream>>>(vwin, vgwin, vrest_ng, vrest_g);

    attn_kernel<<<dim3(16, NH, NW), 128, 0, stream>>>(
        qbuf, kbuf, vbuf, vrest_ng, vrest_g, attbuf);

    split_kernel<<<2048, 256, 0, stream>>>(attbuf, ath, atl, (int)(M2 / 4));

    // out projection: BM=64 -> grid 16x32 = 512 blocks (2/CU)
    gemm_mfma_kernel<64><<<dim3(16, 32), 256, 0, stream>>>(
        ath, atl,
        woh, wol, bo, out,
        woh, wol, bo, out,
        woh, wol, bo, out, HID);
}

// Round 3
// 220.192 us; speedup vs baseline: 3.7509x; 2.4906x over previous
//
#include <hip/hip_runtime.h>
#include <hip/hip_bf16.h>

#define S_LEN   2048
#define HID     1024
#define NH      16
#define HD      64
#define WIN     512
#define NW      4
#define NG      64
#define GSTRIDE 32
#define SCALE   0.125f   // 64^-0.5

typedef __bf16 bf16x8 __attribute__((ext_vector_type(8)));
typedef float  f32x4  __attribute__((ext_vector_type(4)));
typedef unsigned short ushort_t;

// ---------------- fp32 -> bf16 hi/lo split helpers ----------------
__device__ __forceinline__ ushort_t f32_to_bf16_rne(float f) {
    unsigned int u = __float_as_uint(f);
    u = u + 0x7FFFu + ((u >> 16) & 1u);
    return (ushort_t)(u >> 16);
}
__device__ __forceinline__ float bf16_to_f32(ushort_t h) {
    return __uint_as_float(((unsigned int)h) << 16);
}

__global__ __launch_bounds__(256) void split_kernel(
    const float* __restrict__ in, ushort_t* __restrict__ hi,
    ushort_t* __restrict__ lo, int n4)
{
    int i = blockIdx.x * 256 + threadIdx.x;
    if (i >= n4) return;
    float4 f = ((const float4*)in)[i];
    ushort4 h, l;
    h.x = f32_to_bf16_rne(f.x); l.x = f32_to_bf16_rne(f.x - bf16_to_f32(h.x));
    h.y = f32_to_bf16_rne(f.y); l.y = f32_to_bf16_rne(f.y - bf16_to_f32(h.y));
    h.z = f32_to_bf16_rne(f.z); l.z = f32_to_bf16_rne(f.z - bf16_to_f32(h.z));
    h.w = f32_to_bf16_rne(f.w); l.w = f32_to_bf16_rne(f.w - bf16_to_f32(h.w));
    ((ushort4*)hi)[i] = h;
    ((ushort4*)lo)[i] = l;
}

// ---------------- async global -> LDS (16B per lane) ----------------
__device__ __forceinline__ void async16(const ushort_t* g, ushort_t* l) {
    __builtin_amdgcn_global_load_lds(
        (const __attribute__((address_space(1))) void*)g,
        (__attribute__((address_space(3))) void*)l, 16, 0, 0);
}

// ---------------- split-bf16 MFMA GEMM ----------------
// C[M][1024] = A[M][K] @ W[1024][K]^T + bias, per segment (up to 3 segments
// for fused QKV). Also emits bf16 copies: seg0->Cb0 (qb), seg1->Cb1 (kb),
// seg2->vt (per-(window,head) transposed V for the attention PV B-operand).
template <int BM>
__global__ __launch_bounds__(256) void gemm_mfma_kernel(
    const ushort_t* __restrict__ Ahi, const ushort_t* __restrict__ Alo,
    const ushort_t* __restrict__ Bhi0, const ushort_t* __restrict__ Blo0,
    const float* __restrict__ bias0, float* __restrict__ C0,
    const ushort_t* __restrict__ Bhi1, const ushort_t* __restrict__ Blo1,
    const float* __restrict__ bias1, float* __restrict__ C1,
    const ushort_t* __restrict__ Bhi2, const ushort_t* __restrict__ Blo2,
    const float* __restrict__ bias2, float* __restrict__ C2,
    ushort_t* __restrict__ Cb0, ushort_t* __restrict__ Cb1,
    ushort_t* __restrict__ vt, int K)
{
    constexpr int BK = 32;
    constexpr int FI = BM / 32;      // m-frags per wave
    __shared__ ushort_t sAhi[BM * BK];
    __shared__ ushort_t sAlo[BM * BK];
    __shared__ ushort_t sBhi[64 * BK];
    __shared__ ushort_t sBlo[64 * BK];

    const int tid  = threadIdx.x;
    const int lane = tid & 63;
    const int wv   = tid >> 6;
    const int wr   = wv >> 1, wc = wv & 1;
    const int quad = lane >> 4, lm = lane & 15;
    const int seg  = blockIdx.x >> 4;             // 0..2 (fused QKV) or 0
    const int bn   = (blockIdx.x & 15) * 64;      // col base within segment
    const int bm   = blockIdx.y * BM;

    const ushort_t* Bhi = (seg == 0) ? Bhi0 : (seg == 1) ? Bhi1 : Bhi2;
    const ushort_t* Blo = (seg == 0) ? Blo0 : (seg == 1) ? Blo1 : Blo2;
    const float*   bias = (seg == 0) ? bias0 : (seg == 1) ? bias1 : bias2;
    float*            C = (seg == 0) ? C0 : (seg == 1) ? C1 : C2;
    ushort_t*        Cb = (seg == 0) ? Cb0 : (seg == 1) ? Cb1 : nullptr;

    f32x4 acc[FI][2];
#pragma unroll
    for (int i = 0; i < FI; ++i)
#pragma unroll
        for (int j = 0; j < 2; ++j) acc[i][j] = {0.f, 0.f, 0.f, 0.f};

    for (int k0 = 0; k0 < K; k0 += BK) {
        __syncthreads();
#pragma unroll
        for (int t = 0; t < BM / 64; ++t) {
            int c = tid + t * 256;
            int row = c >> 2, kp = c & 3;
            size_t go = (size_t)(bm + row) * K + k0 + kp * 8;
            async16(&Ahi[go], &sAhi[c * 8]);
            async16(&Alo[go], &sAlo[c * 8]);
        }
        {
            int row = tid >> 2, kp = tid & 3;
            size_t go = (size_t)(bn + row) * K + k0 + kp * 8;
            async16(&Bhi[go], &sBhi[tid * 8]);
            async16(&Blo[go], &sBlo[tid * 8]);
        }
        asm volatile("s_waitcnt vmcnt(0)" ::: "memory");
        __syncthreads();

        bf16x8 afh[FI], afl[FI], bfh[2], bfl[2];
#pragma unroll
        for (int i = 0; i < FI; ++i) {
            int row = wr * (BM / 2) + i * 16 + lm;
            afh[i] = *(const bf16x8*)&sAhi[row * BK + quad * 8];
            afl[i] = *(const bf16x8*)&sAlo[row * BK + quad * 8];
        }
#pragma unroll
        for (int j = 0; j < 2; ++j) {
            int row = wc * 32 + j * 16 + lm;
            bfh[j] = *(const bf16x8*)&sBhi[row * BK + quad * 8];
            bfl[j] = *(const bf16x8*)&sBlo[row * BK + quad * 8];
        }
#pragma unroll
        for (int i = 0; i < FI; ++i)
#pragma unroll
            for (int j = 0; j < 2; ++j) {
                acc[i][j] = __builtin_amdgcn_mfma_f32_16x16x32_bf16(afh[i], bfh[j], acc[i][j], 0, 0, 0);
                acc[i][j] = __builtin_amdgcn_mfma_f32_16x16x32_bf16(afh[i], bfl[j], acc[i][j], 0, 0, 0);
                acc[i][j] = __builtin_amdgcn_mfma_f32_16x16x32_bf16(afl[i], bfh[j], acc[i][j], 0, 0, 0);
            }
    }

    // epilogue: C/D layout col=lane&15, row=quad*4+reg
#pragma unroll
    for (int i = 0; i < FI; ++i)
#pragma unroll
        for (int j = 0; j < 2; ++j) {
            int col = bn + wc * 32 + j * 16 + lm;
            float b = bias[col];
#pragma unroll
            for (int r = 0; r < 4; ++r) {
                int row = bm + wr * (BM / 2) + i * 16 + quad * 4 + r;
                float val = acc[i][j][r] + b;
                C[(size_t)row * 1024 + col] = val;
                if (Cb) Cb[(size_t)row * 1024 + col] = f32_to_bf16_rne(val);
                if (vt && seg == 2) {
                    int hh = col >> 6, dd = col & 63, nn = row >> 9, jj = row & 511;
                    vt[(((size_t)nn * NH + hh) * HD + dd) * WIN + jj] = f32_to_bf16_rne(val);
                }
            }
        }
}

// ---------------- per-window / global V sums (zero-score correction) ----
__global__ __launch_bounds__(64) void vsum_kernel(const float* __restrict__ v,
    float* __restrict__ vwin, float* __restrict__ vgwin)
{
    int n = blockIdx.x, h = blockIdx.y, d = threadIdx.x;
    float s = 0.f, sg = 0.f;
    for (int j = 0; j < WIN; ++j) {
        float val = v[(size_t)(n * WIN + j) * HID + h * HD + d];
        s += val;
        if ((j & (GSTRIDE - 1)) == 0) sg += val;
    }
    vwin[(n * NH + h) * HD + d] = s;
    vgwin[(n * NH + h) * HD + d] = sg;
}

__global__ __launch_bounds__(64) void vrest_kernel(
    const float* __restrict__ vwin, const float* __restrict__ vgwin,
    float* __restrict__ vrest_ng, float* __restrict__ vrest_g)
{
    int n = blockIdx.x, h = blockIdx.y, d = threadIdx.x;
    float vall = 0.f, vgall = 0.f;
    for (int n2 = 0; n2 < NW; ++n2) {
        vall += vwin[(n2 * NH + h) * HD + d];
        vgall += vgwin[(n2 * NH + h) * HD + d];
    }
    float w  = vwin[(n * NH + h) * HD + d];
    float gw = vgwin[(n * NH + h) * HD + d];
    vrest_ng[(n * NH + h) * HD + d] = vall - w;
    vrest_g[(n * NH + h) * HD + d]  = vall - w - (vgall - gw);
}

// ---------------- MFMA flash attention ----------------
// Grid (8 qtiles of 64, 16 heads, 4 windows) = 512 blocks, 256 thr = 4 waves.
// Wave w owns 16 queries. Per 128-key chunk: QK^T (16 MFMA, k=64 chained),
// exp on VALU (shift m=0 is safe: |s|<~3), P -> LDS (C-layout -> A-layout
// round-trip within the wave), PV (16 MFMA) into C-layout O accumulator.
// K/Vt staged via global_load_lds with XOR swizzle on the GLOBAL address
// (LDS side stays lane-linear as the instruction requires).
__global__ __launch_bounds__(256) void attn_mfma_kernel(
    const ushort_t* __restrict__ qb, const ushort_t* __restrict__ kb,
    const ushort_t* __restrict__ vtb, const float* __restrict__ vfull,
    const float* __restrict__ vrest_ng, const float* __restrict__ vrest_g,
    ushort_t* __restrict__ ath, ushort_t* __restrict__ atl)
{
    __shared__ __align__(16) ushort_t sK[128 * 64];    // [key][8 chunks of 8 d], xor-swizzled
    __shared__ __align__(16) ushort_t sVt[64 * 128];   // [d][16 chunks of 8 j], xor-swizzled
    __shared__ __align__(16) ushort_t sP[4][16 * 136]; // per-wave P, padded rows
    __shared__ float sPe[96];
    __shared__ float sAe[128];
    __shared__ float sLe[2];

    const int tid  = threadIdx.x;
    const int lane = tid & 63;
    const int w    = tid >> 6;
    const int quad = lane >> 4;
    const int lm   = lane & 15;
    const int tile = blockIdx.x;   // 0..7
    const int h    = blockIdx.y;
    const int n    = blockIdx.z;

    // Q A-fragments straight from global bf16 (each element read once per block)
    const size_t qrow = (size_t)(n * WIN + tile * 64 + w * 16 + lm);
    const bf16x8 aq0 = *(const bf16x8*)&qb[qrow * HID + h * HD + quad * 8];
    const bf16x8 aq1 = *(const bf16x8*)&qb[qrow * HID + h * HD + 32 + quad * 8];

    f32x4 acc[4];
#pragma unroll
    for (int dt = 0; dt < 4; ++dt) acc[dt] = {0.f, 0.f, 0.f, 0.f};
    float lac[4] = {0.f, 0.f, 0.f, 0.f};
    bool qg[4];
#pragma unroll
    for (int r = 0; r < 4; ++r)
        qg[r] = (((tile * 64 + w * 16 + quad * 4 + r) & (GSTRIDE - 1)) == 0);

    ushort_t* sPw = sP[w];

    for (int c = 0; c < 4; ++c) {
        __syncthreads();
#pragma unroll
        for (int t = 0; t < 4; ++t) {
            int c2 = tid + t * 256;
            {   // K chunk: rows = 128 keys x 8 d-chunks; store global chunk (ck^(key&7)) at slot ck
                int key = c2 >> 3, ck = c2 & 7, gc = ck ^ (key & 7);
                async16(&kb[(size_t)(n * WIN + c * 128 + key) * HID + h * HD + gc * 8],
                        &sK[c2 * 8]);
            }
            {   // Vt chunk: 64 d-rows x 16 j-chunks
                int d = c2 >> 4, sl = c2 & 15, gj = sl ^ (d & 15);
                async16(&vtb[((size_t)(n * NH + h) * HD + d) * WIN + c * 128 + gj * 8],
                        &sVt[c2 * 8]);
            }
        }
        asm volatile("s_waitcnt vmcnt(0)" ::: "memory");
        __syncthreads();

        // ---- QK^T + softmax numerators ----
#pragma unroll
        for (int jt = 0; jt < 8; ++jt) {
            int key = jt * 16 + lm;
            bf16x8 bk0 = *(const bf16x8*)&sK[key * 64 + ((quad) ^ (key & 7)) * 8];
            bf16x8 bk1 = *(const bf16x8*)&sK[key * 64 + ((4 + quad) ^ (key & 7)) * 8];
            f32x4 s = {0.f, 0.f, 0.f, 0.f};
            s = __builtin_amdgcn_mfma_f32_16x16x32_bf16(aq0, bk0, s, 0, 0, 0);
            s = __builtin_amdgcn_mfma_f32_16x16x32_bf16(aq1, bk1, s, 0, 0, 0);
            const bool jg = (lm == 0) && ((jt & 1) == 0);   // key % 32 == 0
#pragma unroll
            for (int r = 0; r < 4; ++r) {
                float sv = s[r] * SCALE;
                if (qg[r] && jg) sv += sv;   // in-window global pair: local + identical global dot
                float p = __expf(sv);
                ushort_t ph = f32_to_bf16_rne(p);
                lac[r] += bf16_to_f32(ph);   // denominator consistent with bf16 P
                sPw[(quad * 4 + r) * 136 + jt * 16 + lm] = ph;
            }
        }

        // ---- PV: P (A-layout from LDS, same-wave round-trip) x Vt (B-layout) ----
        bf16x8 pf[4];
#pragma unroll
        for (int jc = 0; jc < 4; ++jc)
            pf[jc] = *(const bf16x8*)&sPw[lm * 136 + jc * 32 + quad * 8];
#pragma unroll
        for (int dt = 0; dt < 4; ++dt) {
            int d = dt * 16 + lm;
#pragma unroll
            for (int jc = 0; jc < 4; ++jc) {
                bf16x8 vf = *(const bf16x8*)&sVt[d * 128 + (((jc * 4 + quad) ^ (d & 15))) * 8];
                acc[dt] = __builtin_amdgcn_mfma_f32_16x16x32_bf16(pf[jc], vf, acc[dt], 0, 0, 0);
            }
        }
    }

    // ---- reduce denominator over the 16 lm lanes (same quad = same query set) ----
#pragma unroll
    for (int r = 0; r < 4; ++r) {
        float l = lac[r];
        l += __shfl_xor(l, 1);
        l += __shfl_xor(l, 2);
        l += __shfl_xor(l, 4);
        l += __shfl_xor(l, 8);
        lac[r] = l;
    }

    // ---- out-of-window global keys for the 2 global queries of this block ----
    __syncthreads();
    if (tid < 96) {
        int gq = tid / 48, kk = tid - gq * 48;
        int g = kk + (kk >= n * 16 ? 16 : 0);   // skip in-window globals
        const ushort_t* qr = &qb[(size_t)(n * WIN + tile * 64 + gq * 32) * HID + h * HD];
        const ushort_t* kr = &kb[(size_t)(g * GSTRIDE) * HID + h * HD];
        float dot = 0.f;
#pragma unroll
        for (int dc = 0; dc < 8; ++dc) {
            bf16x8 qv = *(const bf16x8*)&qr[dc * 8];
            bf16x8 kv = *(const bf16x8*)&kr[dc * 8];
#pragma unroll
            for (int e = 0; e < 8; ++e) dot += (float)qv[e] * (float)kv[e];
        }
        sPe[tid] = __expf(dot * SCALE);
    }
    __syncthreads();
    if (tid < 128) {
        int gq = tid >> 6, d = tid & 63;
        float a = 0.f;
        for (int kk = 0; kk < 48; ++kk) {
            int g = kk + (kk >= n * 16 ? 16 : 0);
            a += sPe[gq * 48 + kk] * vfull[(size_t)(g * GSTRIDE) * HID + h * HD + d];
        }
        sAe[tid] = a;
    } else if (tid < 130) {
        int gq = tid - 128;
        float s = 0.f;
        for (int kk = 0; kk < 48; ++kk) s += sPe[gq * 48 + kk];
        sLe[gq] = s;
    }
    __syncthreads();

    // ---- epilogue: fold zero-score keys, normalize, write split bf16 hi/lo ----
    const float* vr_ng = &vrest_ng[(size_t)(n * NH + h) * HD];
    const float* vr_g  = &vrest_g[(size_t)(n * NH + h) * HD];
#pragma unroll
    for (int r = 0; r < 4; ++r) {
        int qo = w * 16 + quad * 4 + r;          // within 64
        int qwin = tile * 64 + qo;
        bool isg = ((qwin & (GSTRIDE - 1)) == 0);
        int gq = (qo >> 5) & 1;
        float l = lac[r] + (float)(S_LEN - WIN); // exp(0)=1 per non-attended key
        if (isg) l += sLe[gq] - 48.0f;           // 48 extra attended keys replace zeros
        float invl = 1.f / l;
        size_t row = (size_t)(n * WIN + qwin) * HID + h * HD;
#pragma unroll
        for (int dt = 0; dt < 4; ++dt) {
            int d = dt * 16 + lm;
            float o = acc[dt][r] + (isg ? (vr_g[d] + sAe[gq * 64 + d]) : vr_ng[d]);
            o *= invl;
            ushort_t hi = f32_to_bf16_rne(o);
            ushort_t lo = f32_to_bf16_rne(o - bf16_to_f32(hi));
            ath[row + d] = hi;
            atl[row + d] = lo;
        }
    }
}

extern "C" void kernel_launch(void* const* d_in, const int* in_sizes, int n_in,
                              void* d_out, int out_size, void* d_ws, size_t ws_size,
                              hipStream_t stream) {
    const float* x   = (const float*)d_in[0];
    const float* wq  = (const float*)d_in[1];
    const float* bq  = (const float*)d_in[2];
    const float* wk  = (const float*)d_in[3];
    const float* bk_ = (const float*)d_in[4];
    const float* wv  = (const float*)d_in[5];
    const float* bv  = (const float*)d_in[6];
    const float* wo  = (const float*)d_in[7];
    const float* bo  = (const float*)d_in[8];
    float* out = (float*)d_out;

    const size_t M2 = 2u * 1024 * 1024, M1 = 1024 * 1024;
    float* ws = (float*)d_ws;
    float* dump     = ws;                  // fp32 C for q/k segs (never read)
    float* kregion  = ws + M2;             // holds vtb (2M ushorts = 4 MB of 8 MB)
    float* vbuf     = ws + 2 * M2;         // fp32 v (vsum / vrest / extra path)
    float* bfreg    = ws + 3 * M2;         // holds qb + kb (4M ushorts = 8 MB)
    float* vwin     = ws + 4 * M2;
    float* vgwin    = vwin + NW * NH * HD;
    float* vrest_ng = vgwin + NW * NH * HD;
    float* vrest_g  = vrest_ng + NW * NH * HD;
    ushort_t* vtb = (ushort_t*)kregion;
    ushort_t* qb  = (ushort_t*)bfreg;
    ushort_t* kb  = qb + M2;
    ushort_t* us = (ushort_t*)(ws + 4 * M2 + 16384);
    ushort_t* xhi = us;            ushort_t* xlo = xhi + M2;
    ushort_t* wqh = xlo + M2;      ushort_t* wql = wqh + M1;
    ushort_t* wkh = wql + M1;      ushort_t* wkl = wkh + M1;
    ushort_t* wvh = wkl + M1;      ushort_t* wvl = wvh + M1;
    ushort_t* woh = wvl + M1;      ushort_t* wol = woh + M1;
    ushort_t* ath = wol + M1;      ushort_t* atl = ath + M2;

    split_kernel<<<2048, 256, 0, stream>>>(x,  xhi, xlo, (int)(M2 / 4));
    split_kernel<<<1024, 256, 0, stream>>>(wq, wqh, wql, (int)(M1 / 4));
    split_kernel<<<1024, 256, 0, stream>>>(wk, wkh, wkl, (int)(M1 / 4));
    split_kernel<<<1024, 256, 0, stream>>>(wv, wvh, wvl, (int)(M1 / 4));
    split_kernel<<<1024, 256, 0, stream>>>(wo, woh, wol, (int)(M1 / 4));

    // fused QKV: N = 3x1024, grid 48x16 = 768 blocks; bf16 q/k + transposed bf16 V out
    gemm_mfma_kernel<128><<<dim3(48, 16), 256, 0, stream>>>(
        xhi, xlo,
        wqh, wql, bq,  dump,
        wkh, wkl, bk_, dump,
        wvh, wvl, bv,  vbuf,
        qb, kb, vtb, HID);

    vsum_kernel<<<dim3(NW, NH), 64, 0, stream>>>(vbuf, vwin, vgwin);
    vrest_kernel<<<dim3(NW, NH), 64, 0, stream>>>(vwin, vgwin, vrest_ng, vrest_g);

    attn_mfma_kernel<<<dim3(8, NH, NW), 256, 0, stream>>>(
        qb, kb, vtb, vbuf, vrest_ng, vrest_g, ath, atl);

    // out projection: BM=64 -> grid 16x32 = 512 blocks
    gemm_mfma_kernel<64><<<dim3(16, 32), 256, 0, stream>>>(
        ath, atl,
        woh, wol, bo, out,
        woh, wol, bo, out,
        woh, wol, bo, out,
        nullptr, nullptr, nullptr, HID);
}

// Round 4
// 218.308 us; speedup vs baseline: 3.7833x; 1.0086x over previous
//
#include <hip/hip_runtime.h>
#include <hip/hip_bf16.h>

#define S_LEN   2048
#define HID     1024
#define NH      16
#define HD      64
#define WIN     512
#define NW      4
#define NG      64
#define GSTRIDE 32
#define SCALE   0.125f   // 64^-0.5

typedef __bf16 bf16x8 __attribute__((ext_vector_type(8)));
typedef float  f32x4  __attribute__((ext_vector_type(4)));
typedef unsigned short ushort_t;

// ---------------- fp32 -> bf16 hi/lo split helpers ----------------
__device__ __forceinline__ ushort_t f32_to_bf16_rne(float f) {
    unsigned int u = __float_as_uint(f);
    u = u + 0x7FFFu + ((u >> 16) & 1u);
    return (ushort_t)(u >> 16);
}
__device__ __forceinline__ float bf16_to_f32(ushort_t h) {
    return __uint_as_float(((unsigned int)h) << 16);
}

// ---------------- batched split: 5 tensors in one launch ----------------
struct SplitJobs {
    const float* in[5];
    ushort_t* hi[5];
    ushort_t* lo[5];
    int n4[5];
};

__global__ __launch_bounds__(256) void split_all_kernel(SplitJobs jobs) {
    int j = blockIdx.y;
    int i = blockIdx.x * 256 + threadIdx.x;
    if (i >= jobs.n4[j]) return;
    float4 f = ((const float4*)jobs.in[j])[i];
    ushort4 h, l;
    h.x = f32_to_bf16_rne(f.x); l.x = f32_to_bf16_rne(f.x - bf16_to_f32(h.x));
    h.y = f32_to_bf16_rne(f.y); l.y = f32_to_bf16_rne(f.y - bf16_to_f32(h.y));
    h.z = f32_to_bf16_rne(f.z); l.z = f32_to_bf16_rne(f.z - bf16_to_f32(h.z));
    h.w = f32_to_bf16_rne(f.w); l.w = f32_to_bf16_rne(f.w - bf16_to_f32(h.w));
    ((ushort4*)jobs.hi[j])[i] = h;
    ((ushort4*)jobs.lo[j])[i] = l;
}

// ---------------- async global -> LDS (16B per lane) ----------------
__device__ __forceinline__ void async16(const ushort_t* g, ushort_t* l) {
    __builtin_amdgcn_global_load_lds(
        (const __attribute__((address_space(1))) void*)g,
        (__attribute__((address_space(3))) void*)l, 16, 0, 0);
}

// ---------------- split-bf16 MFMA GEMM ----------------
// C[M][1024] = A[M][K] @ W[1024][K]^T + bias, per segment (up to 3 segments
// for fused QKV). acc += Ahi*Bhi + Ahi*Blo + Alo*Bhi.
// Tile BM x BN, BK=32, 256 thr = 4 waves (2x2), wave tile (BM/2)x(BN/2).
// LDS rows hold 4 chunks of 16B; the GLOBAL chunk index is XOR-swizzled
// (gc = kp ^ ((row>>1)&3)) so fragment ds_read_b128 covers all 8 bank
// phases uniformly (conflict-free) while staying global_load_lds-compatible
// (a row's 4 chunks permute within one 64B line -> coalescing preserved).
// Optional bf16 outputs: Cb0 (seg0), Cb1 (seg1), vt (seg2, transposed V).
template <int BM, int BN>
__global__ __launch_bounds__(256) void gemm_mfma_kernel(
    const ushort_t* __restrict__ Ahi, const ushort_t* __restrict__ Alo,
    const ushort_t* __restrict__ Bhi0, const ushort_t* __restrict__ Blo0,
    const float* __restrict__ bias0, float* __restrict__ C0,
    const ushort_t* __restrict__ Bhi1, const ushort_t* __restrict__ Blo1,
    const float* __restrict__ bias1, float* __restrict__ C1,
    const ushort_t* __restrict__ Bhi2, const ushort_t* __restrict__ Blo2,
    const float* __restrict__ bias2, float* __restrict__ C2,
    ushort_t* __restrict__ Cb0, ushort_t* __restrict__ Cb1,
    ushort_t* __restrict__ vt, int K)
{
    constexpr int BK  = 32;
    constexpr int FI  = BM / 32;         // m-frags per wave
    constexpr int FJ  = BN / 32;         // n-frags per wave
    constexpr int CPS = 1024 / BN;       // col-blocks per segment
    __shared__ ushort_t sAhi[BM * BK];
    __shared__ ushort_t sAlo[BM * BK];
    __shared__ ushort_t sBhi[BN * BK];
    __shared__ ushort_t sBlo[BN * BK];

    const int tid  = threadIdx.x;
    const int lane = tid & 63;
    const int wv   = tid >> 6;
    const int wr   = wv >> 1, wc = wv & 1;
    const int quad = lane >> 4, lm = lane & 15;
    const int seg  = blockIdx.x / CPS;            // 0..2 (fused QKV) or 0
    const int bn   = (blockIdx.x % CPS) * BN;     // col base within segment
    const int bm   = blockIdx.y * BM;

    const ushort_t* Bhi = (seg == 0) ? Bhi0 : (seg == 1) ? Bhi1 : Bhi2;
    const ushort_t* Blo = (seg == 0) ? Blo0 : (seg == 1) ? Blo1 : Blo2;
    const float*   bias = (seg == 0) ? bias0 : (seg == 1) ? bias1 : bias2;
    float*            C = (seg == 0) ? C0 : (seg == 1) ? C1 : C2;
    ushort_t*        Cb = (seg == 0) ? Cb0 : (seg == 1) ? Cb1 : nullptr;

    f32x4 acc[FI][FJ];
#pragma unroll
    for (int i = 0; i < FI; ++i)
#pragma unroll
        for (int j = 0; j < FJ; ++j) acc[i][j] = {0.f, 0.f, 0.f, 0.f};

    for (int k0 = 0; k0 < K; k0 += BK) {
        __syncthreads();
#pragma unroll
        for (int t = 0; t < BM / 64; ++t) {
            int c = tid + t * 256;
            int row = c >> 2, kp = c & 3, gc = kp ^ ((row >> 1) & 3);
            size_t go = (size_t)(bm + row) * K + k0 + gc * 8;
            async16(&Ahi[go], &sAhi[c * 8]);
            async16(&Alo[go], &sAlo[c * 8]);
        }
#pragma unroll
        for (int t = 0; t < BN / 64; ++t) {
            int c = tid + t * 256;
            int row = c >> 2, kp = c & 3, gc = kp ^ ((row >> 1) & 3);
            size_t go = (size_t)(bn + row) * K + k0 + gc * 8;
            async16(&Bhi[go], &sBhi[c * 8]);
            async16(&Blo[go], &sBlo[c * 8]);
        }
        asm volatile("s_waitcnt vmcnt(0)" ::: "memory");
        __syncthreads();

        bf16x8 afh[FI], afl[FI], bfh[FJ], bfl[FJ];
#pragma unroll
        for (int i = 0; i < FI; ++i) {
            int row = wr * (BM / 2) + i * 16 + lm;
            int slot = quad ^ ((row >> 1) & 3);
            afh[i] = *(const bf16x8*)&sAhi[row * BK + slot * 8];
            afl[i] = *(const bf16x8*)&sAlo[row * BK + slot * 8];
        }
#pragma unroll
        for (int j = 0; j < FJ; ++j) {
            int row = wc * (BN / 2) + j * 16 + lm;
            int slot = quad ^ ((row >> 1) & 3);
            bfh[j] = *(const bf16x8*)&sBhi[row * BK + slot * 8];
            bfl[j] = *(const bf16x8*)&sBlo[row * BK + slot * 8];
        }
#pragma unroll
        for (int i = 0; i < FI; ++i)
#pragma unroll
            for (int j = 0; j < FJ; ++j) {
                acc[i][j] = __builtin_amdgcn_mfma_f32_16x16x32_bf16(afh[i], bfh[j], acc[i][j], 0, 0, 0);
                acc[i][j] = __builtin_amdgcn_mfma_f32_16x16x32_bf16(afh[i], bfl[j], acc[i][j], 0, 0, 0);
                acc[i][j] = __builtin_amdgcn_mfma_f32_16x16x32_bf16(afl[i], bfh[j], acc[i][j], 0, 0, 0);
            }
    }

    // epilogue: C/D layout col=lane&15, row=quad*4+reg
#pragma unroll
    for (int i = 0; i < FI; ++i)
#pragma unroll
        for (int j = 0; j < FJ; ++j) {
            int col = bn + wc * (BN / 2) + j * 16 + lm;
            float b = bias[col];
#pragma unroll
            for (int r = 0; r < 4; ++r) {
                int row = bm + wr * (BM / 2) + i * 16 + quad * 4 + r;
                float val = acc[i][j][r] + b;
                if (C)  C[(size_t)row * 1024 + col] = val;
                if (Cb) Cb[(size_t)row * 1024 + col] = f32_to_bf16_rne(val);
                if (vt && seg == 2) {
                    int hh = col >> 6, dd = col & 63, nn = row >> 9, jj = row & 511;
                    vt[(((size_t)nn * NH + hh) * HD + dd) * WIN + jj] = f32_to_bf16_rne(val);
                }
            }
        }
}

// ---------------- per-window / global V sums (zero-score correction) ----
__global__ __launch_bounds__(64) void vsum_kernel(const float* __restrict__ v,
    float* __restrict__ vwin, float* __restrict__ vgwin)
{
    int n = blockIdx.x, h = blockIdx.y, d = threadIdx.x;
    float s = 0.f, sg = 0.f;
    for (int j = 0; j < WIN; ++j) {
        float val = v[(size_t)(n * WIN + j) * HID + h * HD + d];
        s += val;
        if ((j & (GSTRIDE - 1)) == 0) sg += val;
    }
    vwin[(n * NH + h) * HD + d] = s;
    vgwin[(n * NH + h) * HD + d] = sg;
}

__global__ __launch_bounds__(64) void vrest_kernel(
    const float* __restrict__ vwin, const float* __restrict__ vgwin,
    float* __restrict__ vrest_ng, float* __restrict__ vrest_g)
{
    int n = blockIdx.x, h = blockIdx.y, d = threadIdx.x;
    float vall = 0.f, vgall = 0.f;
    for (int n2 = 0; n2 < NW; ++n2) {
        vall += vwin[(n2 * NH + h) * HD + d];
        vgall += vgwin[(n2 * NH + h) * HD + d];
    }
    float w  = vwin[(n * NH + h) * HD + d];
    float gw = vgwin[(n * NH + h) * HD + d];
    vrest_ng[(n * NH + h) * HD + d] = vall - w;
    vrest_g[(n * NH + h) * HD + d]  = vall - w - (vgall - gw);
}

// ---------------- MFMA flash attention (unchanged from round 3) ----------------
__global__ __launch_bounds__(256) void attn_mfma_kernel(
    const ushort_t* __restrict__ qb, const ushort_t* __restrict__ kb,
    const ushort_t* __restrict__ vtb, const float* __restrict__ vfull,
    const float* __restrict__ vrest_ng, const float* __restrict__ vrest_g,
    ushort_t* __restrict__ ath, ushort_t* __restrict__ atl)
{
    __shared__ __align__(16) ushort_t sK[128 * 64];    // [key][8 chunks of 8 d], xor-swizzled
    __shared__ __align__(16) ushort_t sVt[64 * 128];   // [d][16 chunks of 8 j], xor-swizzled
    __shared__ __align__(16) ushort_t sP[4][16 * 136]; // per-wave P, padded rows
    __shared__ float sPe[96];
    __shared__ float sAe[128];
    __shared__ float sLe[2];

    const int tid  = threadIdx.x;
    const int lane = tid & 63;
    const int w    = tid >> 6;
    const int quad = lane >> 4;
    const int lm   = lane & 15;
    const int tile = blockIdx.x;   // 0..7
    const int h    = blockIdx.y;
    const int n    = blockIdx.z;

    const size_t qrow = (size_t)(n * WIN + tile * 64 + w * 16 + lm);
    const bf16x8 aq0 = *(const bf16x8*)&qb[qrow * HID + h * HD + quad * 8];
    const bf16x8 aq1 = *(const bf16x8*)&qb[qrow * HID + h * HD + 32 + quad * 8];

    f32x4 acc[4];
#pragma unroll
    for (int dt = 0; dt < 4; ++dt) acc[dt] = {0.f, 0.f, 0.f, 0.f};
    float lac[4] = {0.f, 0.f, 0.f, 0.f};
    bool qg[4];
#pragma unroll
    for (int r = 0; r < 4; ++r)
        qg[r] = (((tile * 64 + w * 16 + quad * 4 + r) & (GSTRIDE - 1)) == 0);

    ushort_t* sPw = sP[w];

    for (int c = 0; c < 4; ++c) {
        __syncthreads();
#pragma unroll
        for (int t = 0; t < 4; ++t) {
            int c2 = tid + t * 256;
            {
                int key = c2 >> 3, ck = c2 & 7, gc = ck ^ (key & 7);
                async16(&kb[(size_t)(n * WIN + c * 128 + key) * HID + h * HD + gc * 8],
                        &sK[c2 * 8]);
            }
            {
                int d = c2 >> 4, sl = c2 & 15, gj = sl ^ (d & 15);
                async16(&vtb[((size_t)(n * NH + h) * HD + d) * WIN + c * 128 + gj * 8],
                        &sVt[c2 * 8]);
            }
        }
        asm volatile("s_waitcnt vmcnt(0)" ::: "memory");
        __syncthreads();

        // ---- QK^T + softmax numerators ----
#pragma unroll
        for (int jt = 0; jt < 8; ++jt) {
            int key = jt * 16 + lm;
            bf16x8 bk0 = *(const bf16x8*)&sK[key * 64 + ((quad) ^ (key & 7)) * 8];
            bf16x8 bk1 = *(const bf16x8*)&sK[key * 64 + ((4 + quad) ^ (key & 7)) * 8];
            f32x4 s = {0.f, 0.f, 0.f, 0.f};
            s = __builtin_amdgcn_mfma_f32_16x16x32_bf16(aq0, bk0, s, 0, 0, 0);
            s = __builtin_amdgcn_mfma_f32_16x16x32_bf16(aq1, bk1, s, 0, 0, 0);
            const bool jg = (lm == 0) && ((jt & 1) == 0);   // key % 32 == 0
#pragma unroll
            for (int r = 0; r < 4; ++r) {
                float sv = s[r] * SCALE;
                if (qg[r] && jg) sv += sv;
                float p = __expf(sv);
                ushort_t ph = f32_to_bf16_rne(p);
                lac[r] += bf16_to_f32(ph);
                sPw[(quad * 4 + r) * 136 + jt * 16 + lm] = ph;
            }
        }

        // ---- PV ----
        bf16x8 pf[4];
#pragma unroll
        for (int jc = 0; jc < 4; ++jc)
            pf[jc] = *(const bf16x8*)&sPw[lm * 136 + jc * 32 + quad * 8];
#pragma unroll
        for (int dt = 0; dt < 4; ++dt) {
            int d = dt * 16 + lm;
#pragma unroll
            for (int jc = 0; jc < 4; ++jc) {
                bf16x8 vf = *(const bf16x8*)&sVt[d * 128 + (((jc * 4 + quad) ^ (d & 15))) * 8];
                acc[dt] = __builtin_amdgcn_mfma_f32_16x16x32_bf16(pf[jc], vf, acc[dt], 0, 0, 0);
            }
        }
    }

#pragma unroll
    for (int r = 0; r < 4; ++r) {
        float l = lac[r];
        l += __shfl_xor(l, 1);
        l += __shfl_xor(l, 2);
        l += __shfl_xor(l, 4);
        l += __shfl_xor(l, 8);
        lac[r] = l;
    }

    // ---- out-of-window global keys for the 2 global queries of this block ----
    __syncthreads();
    if (tid < 96) {
        int gq = tid / 48, kk = tid - gq * 48;
        int g = kk + (kk >= n * 16 ? 16 : 0);
        const ushort_t* qr = &qb[(size_t)(n * WIN + tile * 64 + gq * 32) * HID + h * HD];
        const ushort_t* kr = &kb[(size_t)(g * GSTRIDE) * HID + h * HD];
        float dot = 0.f;
#pragma unroll
        for (int dc = 0; dc < 8; ++dc) {
            bf16x8 qv = *(const bf16x8*)&qr[dc * 8];
            bf16x8 kv = *(const bf16x8*)&kr[dc * 8];
#pragma unroll
            for (int e = 0; e < 8; ++e) dot += (float)qv[e] * (float)kv[e];
        }
        sPe[tid] = __expf(dot * SCALE);
    }
    __syncthreads();
    if (tid < 128) {
        int gq = tid >> 6, d = tid & 63;
        float a = 0.f;
        for (int kk = 0; kk < 48; ++kk) {
            int g = kk + (kk >= n * 16 ? 16 : 0);
            a += sPe[gq * 48 + kk] * vfull[(size_t)(g * GSTRIDE) * HID + h * HD + d];
        }
        sAe[tid] = a;
    } else if (tid < 130) {
        int gq = tid - 128;
        float s = 0.f;
        for (int kk = 0; kk < 48; ++kk) s += sPe[gq * 48 + kk];
        sLe[gq] = s;
    }
    __syncthreads();

    // ---- epilogue ----
    const float* vr_ng = &vrest_ng[(size_t)(n * NH + h) * HD];
    const float* vr_g  = &vrest_g[(size_t)(n * NH + h) * HD];
#pragma unroll
    for (int r = 0; r < 4; ++r) {
        int qo = w * 16 + quad * 4 + r;
        int qwin = tile * 64 + qo;
        bool isg = ((qwin & (GSTRIDE - 1)) == 0);
        int gq = (qo >> 5) & 1;
        float l = lac[r] + (float)(S_LEN - WIN);
        if (isg) l += sLe[gq] - 48.0f;
        float invl = 1.f / l;
        size_t row = (size_t)(n * WIN + qwin) * HID + h * HD;
#pragma unroll
        for (int dt = 0; dt < 4; ++dt) {
            int d = dt * 16 + lm;
            float o = acc[dt][r] + (isg ? (vr_g[d] + sAe[gq * 64 + d]) : vr_ng[d]);
            o *= invl;
            ushort_t hi = f32_to_bf16_rne(o);
            ushort_t lo = f32_to_bf16_rne(o - bf16_to_f32(hi));
            ath[row + d] = hi;
            atl[row + d] = lo;
        }
    }
}

extern "C" void kernel_launch(void* const* d_in, const int* in_sizes, int n_in,
                              void* d_out, int out_size, void* d_ws, size_t ws_size,
                              hipStream_t stream) {
    const float* x   = (const float*)d_in[0];
    const float* wq  = (const float*)d_in[1];
    const float* bq  = (const float*)d_in[2];
    const float* wk  = (const float*)d_in[3];
    const float* bk_ = (const float*)d_in[4];
    const float* wv  = (const float*)d_in[5];
    const float* bv  = (const float*)d_in[6];
    const float* wo  = (const float*)d_in[7];
    const float* bo  = (const float*)d_in[8];
    float* out = (float*)d_out;

    const size_t M2 = 2u * 1024 * 1024, M1 = 1024 * 1024;
    float* ws = (float*)d_ws;
    float* kregion  = ws + M2;             // holds vtb
    float* vbuf     = ws + 2 * M2;         // fp32 v
    float* bfreg    = ws + 3 * M2;         // holds qb + kb
    float* vwin     = ws + 4 * M2;
    float* vgwin    = vwin + NW * NH * HD;
    float* vrest_ng = vgwin + NW * NH * HD;
    float* vrest_g  = vrest_ng + NW * NH * HD;
    ushort_t* vtb = (ushort_t*)kregion;
    ushort_t* qb  = (ushort_t*)bfreg;
    ushort_t* kb  = qb + M2;
    ushort_t* us = (ushort_t*)(ws + 4 * M2 + 16384);
    ushort_t* xhi = us;            ushort_t* xlo = xhi + M2;
    ushort_t* wqh = xlo + M2;      ushort_t* wql = wqh + M1;
    ushort_t* wkh = wql + M1;      ushort_t* wkl = wkh + M1;
    ushort_t* wvh = wkl + M1;      ushort_t* wvl = wvh + M1;
    ushort_t* woh = wvl + M1;      ushort_t* wol = woh + M1;
    ushort_t* ath = wol + M1;      ushort_t* atl = ath + M2;

    SplitJobs jobs;
    jobs.in[0] = x;  jobs.hi[0] = xhi; jobs.lo[0] = xlo; jobs.n4[0] = (int)(M2 / 4);
    jobs.in[1] = wq; jobs.hi[1] = wqh; jobs.lo[1] = wql; jobs.n4[1] = (int)(M1 / 4);
    jobs.in[2] = wk; jobs.hi[2] = wkh; jobs.lo[2] = wkl; jobs.n4[2] = (int)(M1 / 4);
    jobs.in[3] = wv; jobs.hi[3] = wvh; jobs.lo[3] = wvl; jobs.n4[3] = (int)(M1 / 4);
    jobs.in[4] = wo; jobs.hi[4] = woh; jobs.lo[4] = wol; jobs.n4[4] = (int)(M1 / 4);
    split_all_kernel<<<dim3(2048, 5), 256, 0, stream>>>(jobs);

    // fused QKV: tile 128x128, grid (3 segs x 8 colblocks) x 16 rowblocks = 384 blocks
    gemm_mfma_kernel<128, 128><<<dim3(24, 16), 256, 0, stream>>>(
        xhi, xlo,
        wqh, wql, bq,  nullptr,
        wkh, wkl, bk_, nullptr,
        wvh, wvl, bv,  vbuf,
        qb, kb, vtb, HID);

    vsum_kernel<<<dim3(NW, NH), 64, 0, stream>>>(vbuf, vwin, vgwin);
    vrest_kernel<<<dim3(NW, NH), 64, 0, stream>>>(vwin, vgwin, vrest_ng, vrest_g);

    attn_mfma_kernel<<<dim3(8, NH, NW), 256, 0, stream>>>(
        qb, kb, vtb, vbuf, vrest_ng, vrest_g, ath, atl);

    // out projection: tile 64x64, grid 16 x 32 = 512 blocks (2/CU)
    gemm_mfma_kernel<64, 64><<<dim3(16, 32), 256, 0, stream>>>(
        ath, atl,
        woh, wol, bo, out,
        woh, wol, bo, out,
        woh, wol, bo, out,
        nullptr, nullptr, nullptr, HID);
}

// Round 5
// 189.706 us; speedup vs baseline: 4.3537x; 1.1508x over previous
//
#include <hip/hip_runtime.h>
#include <hip/hip_bf16.h>

#define S_LEN   2048
#define HID     1024
#define NH      16
#define HD      64
#define WIN     512
#define NW      4
#define NG      64
#define GSTRIDE 32
#define SCALE   0.125f   // 64^-0.5

typedef __bf16 bf16x8 __attribute__((ext_vector_type(8)));
typedef float  f32x4  __attribute__((ext_vector_type(4)));
typedef unsigned short ushort_t;

// ---------------- fp32 -> bf16 helpers ----------------
__device__ __forceinline__ ushort_t f32_to_bf16_rne(float f) {
    unsigned int u = __float_as_uint(f);
    u = u + 0x7FFFu + ((u >> 16) & 1u);
    return (ushort_t)(u >> 16);
}
__device__ __forceinline__ float bf16_to_f32(ushort_t h) {
    return __uint_as_float(((unsigned int)h) << 16);
}

// ---------------- batched cast: 5 tensors fp32 -> bf16 in one launch ----------------
struct CastJobs {
    const float* in[5];
    ushort_t* hi[5];
    int n4[5];
};

__global__ __launch_bounds__(256) void cast_all_kernel(CastJobs jobs) {
    int j = blockIdx.y;
    int i = blockIdx.x * 256 + threadIdx.x;
    if (i >= jobs.n4[j]) return;
    float4 f = ((const float4*)jobs.in[j])[i];
    ushort4 h;
    h.x = f32_to_bf16_rne(f.x);
    h.y = f32_to_bf16_rne(f.y);
    h.z = f32_to_bf16_rne(f.z);
    h.w = f32_to_bf16_rne(f.w);
    ((ushort4*)jobs.hi[j])[i] = h;
}

// ---------------- async global -> LDS (16B per lane) ----------------
__device__ __forceinline__ void async16(const ushort_t* g, ushort_t* l) {
    __builtin_amdgcn_global_load_lds(
        (const __attribute__((address_space(1))) void*)g,
        (__attribute__((address_space(3))) void*)l, 16, 0, 0);
}

// ============== single-bf16 MFMA GEMM, 128x64 block, 2 waves ==============
// Wave w computes a full 64x64 tile (FI=FJ=4): 16 MFMA per 8 ds_read_b128
// per BK=32 step -> 32 FLOP/LDS-byte (above the ~26 FLOP/B LDS-parity line).
// XOR swizzle on the GLOBAL chunk index keeps frag reads 2-way max (free).

// --- QKV variant: 3 weight segments, bf16 q/k outputs, fp32 v + transposed bf16 V ---
__global__ __launch_bounds__(128) void gemm_qkv_kernel(
    const ushort_t* __restrict__ xb,
    const ushort_t* __restrict__ wqb, const float* __restrict__ bq,
    const ushort_t* __restrict__ wkb, const float* __restrict__ bk,
    const ushort_t* __restrict__ wvb, const float* __restrict__ bv,
    ushort_t* __restrict__ qb, ushort_t* __restrict__ kb,
    float* __restrict__ vbuf, ushort_t* __restrict__ vtb)
{
    __shared__ ushort_t sA[128 * 32];
    __shared__ ushort_t sB[64 * 32];
    const int tid  = threadIdx.x;
    const int lane = tid & 63;
    const int w    = tid >> 6;
    const int quad = lane >> 4, lm = lane & 15;
    const int seg  = blockIdx.x >> 4;
    const int bn   = (blockIdx.x & 15) * 64;
    const int bm   = blockIdx.y * 128;

    const ushort_t* B  = (seg == 0) ? wqb : (seg == 1) ? wkb : wvb;
    const float* bias  = (seg == 0) ? bq  : (seg == 1) ? bk  : bv;

    f32x4 acc[4][4];
#pragma unroll
    for (int i = 0; i < 4; ++i)
#pragma unroll
        for (int j = 0; j < 4; ++j) acc[i][j] = {0.f, 0.f, 0.f, 0.f};

    for (int k0 = 0; k0 < HID; k0 += 32) {
        __syncthreads();
#pragma unroll
        for (int t = 0; t < 4; ++t) {          // A: 512 chunks, 4/thread
            int c = tid + t * 128;
            int row = c >> 2, kp = c & 3, gc = kp ^ ((row >> 1) & 3);
            async16(&xb[(size_t)(bm + row) * HID + k0 + gc * 8], &sA[c * 8]);
        }
#pragma unroll
        for (int t = 0; t < 2; ++t) {          // B: 256 chunks, 2/thread
            int c = tid + t * 128;
            int row = c >> 2, kp = c & 3, gc = kp ^ ((row >> 1) & 3);
            async16(&B[(size_t)(bn + row) * HID + k0 + gc * 8], &sB[c * 8]);
        }
        asm volatile("s_waitcnt vmcnt(0)" ::: "memory");
        __syncthreads();

        bf16x8 af[4], bf[4];
#pragma unroll
        for (int i = 0; i < 4; ++i) {
            int row = w * 64 + i * 16 + lm;
            int slot = quad ^ ((row >> 1) & 3);
            af[i] = *(const bf16x8*)&sA[row * 32 + slot * 8];
        }
#pragma unroll
        for (int j = 0; j < 4; ++j) {
            int row = j * 16 + lm;
            int slot = quad ^ ((row >> 1) & 3);
            bf[j] = *(const bf16x8*)&sB[row * 32 + slot * 8];
        }
#pragma unroll
        for (int i = 0; i < 4; ++i)
#pragma unroll
            for (int j = 0; j < 4; ++j)
                acc[i][j] = __builtin_amdgcn_mfma_f32_16x16x32_bf16(af[i], bf[j], acc[i][j], 0, 0, 0);
    }

    // epilogue: C/D layout col=lane&15, row=quad*4+reg
#pragma unroll
    for (int i = 0; i < 4; ++i)
#pragma unroll
        for (int j = 0; j < 4; ++j) {
            int col = bn + j * 16 + lm;
            float b = bias[col];
#pragma unroll
            for (int r = 0; r < 4; ++r) {
                int row = bm + w * 64 + i * 16 + quad * 4 + r;
                float val = acc[i][j][r] + b;
                if (seg == 0) {
                    qb[(size_t)row * HID + col] = f32_to_bf16_rne(val);
                } else if (seg == 1) {
                    kb[(size_t)row * HID + col] = f32_to_bf16_rne(val);
                } else {
                    vbuf[(size_t)row * HID + col] = val;
                    int hh = col >> 6, dd = col & 63, nn = row >> 9, jj = row & 511;
                    vtb[(((size_t)nn * NH + hh) * HD + dd) * WIN + jj] = f32_to_bf16_rne(val);
                }
            }
        }
}

// --- out-proj variant: K-split-2, fp32 partials (bias added in reduce) ---
__global__ __launch_bounds__(128) void gemm_out_kernel(
    const ushort_t* __restrict__ A, const ushort_t* __restrict__ B,
    float* __restrict__ part)   // part[z][2048][1024]
{
    __shared__ ushort_t sA[128 * 32];
    __shared__ ushort_t sB[64 * 32];
    const int tid  = threadIdx.x;
    const int lane = tid & 63;
    const int w    = tid >> 6;
    const int quad = lane >> 4, lm = lane & 15;
    const int bn   = blockIdx.x * 64;
    const int bm   = blockIdx.y * 128;
    const int kz   = blockIdx.z;           // 0..1
    float* P = part + (size_t)kz * S_LEN * HID;

    f32x4 acc[4][4];
#pragma unroll
    for (int i = 0; i < 4; ++i)
#pragma unroll
        for (int j = 0; j < 4; ++j) acc[i][j] = {0.f, 0.f, 0.f, 0.f};

    for (int k0 = kz * 512; k0 < kz * 512 + 512; k0 += 32) {
        __syncthreads();
#pragma unroll
        for (int t = 0; t < 4; ++t) {
            int c = tid + t * 128;
            int row = c >> 2, kp = c & 3, gc = kp ^ ((row >> 1) & 3);
            async16(&A[(size_t)(bm + row) * HID + k0 + gc * 8], &sA[c * 8]);
        }
#pragma unroll
        for (int t = 0; t < 2; ++t) {
            int c = tid + t * 128;
            int row = c >> 2, kp = c & 3, gc = kp ^ ((row >> 1) & 3);
            async16(&B[(size_t)(bn + row) * HID + k0 + gc * 8], &sB[c * 8]);
        }
        asm volatile("s_waitcnt vmcnt(0)" ::: "memory");
        __syncthreads();

        bf16x8 af[4], bf[4];
#pragma unroll
        for (int i = 0; i < 4; ++i) {
            int row = w * 64 + i * 16 + lm;
            int slot = quad ^ ((row >> 1) & 3);
            af[i] = *(const bf16x8*)&sA[row * 32 + slot * 8];
        }
#pragma unroll
        for (int j = 0; j < 4; ++j) {
            int row = j * 16 + lm;
            int slot = quad ^ ((row >> 1) & 3);
            bf[j] = *(const bf16x8*)&sB[row * 32 + slot * 8];
        }
#pragma unroll
        for (int i = 0; i < 4; ++i)
#pragma unroll
            for (int j = 0; j < 4; ++j)
                acc[i][j] = __builtin_amdgcn_mfma_f32_16x16x32_bf16(af[i], bf[j], acc[i][j], 0, 0, 0);
    }

#pragma unroll
    for (int i = 0; i < 4; ++i)
#pragma unroll
        for (int j = 0; j < 4; ++j) {
            int col = bn + j * 16 + lm;
#pragma unroll
            for (int r = 0; r < 4; ++r) {
                int row = bm + w * 64 + i * 16 + quad * 4 + r;
                P[(size_t)row * HID + col] = acc[i][j][r];
            }
        }
}

__global__ __launch_bounds__(256) void reduce_bias_kernel(
    const float* __restrict__ part, const float* __restrict__ bias,
    float* __restrict__ out, int n4)
{
    int i = blockIdx.x * 256 + threadIdx.x;
    if (i >= n4) return;
    float4 a = ((const float4*)part)[i];
    float4 b = ((const float4*)(part + (size_t)S_LEN * HID))[i];
    int col = (i * 4) & (HID - 1);
    float4 bs = *(const float4*)&bias[col];
    float4 o;
    o.x = a.x + b.x + bs.x; o.y = a.y + b.y + bs.y;
    o.z = a.z + b.z + bs.z; o.w = a.w + b.w + bs.w;
    ((float4*)out)[i] = o;
}

// ---------------- per-window / global V sums (zero-score correction) ----
__global__ __launch_bounds__(64) void vsum_kernel(const float* __restrict__ v,
    float* __restrict__ vwin, float* __restrict__ vgwin)
{
    int n = blockIdx.x, h = blockIdx.y, d = threadIdx.x;
    float s = 0.f, sg = 0.f;
    for (int j = 0; j < WIN; ++j) {
        float val = v[(size_t)(n * WIN + j) * HID + h * HD + d];
        s += val;
        if ((j & (GSTRIDE - 1)) == 0) sg += val;
    }
    vwin[(n * NH + h) * HD + d] = s;
    vgwin[(n * NH + h) * HD + d] = sg;
}

__global__ __launch_bounds__(64) void vrest_kernel(
    const float* __restrict__ vwin, const float* __restrict__ vgwin,
    float* __restrict__ vrest_ng, float* __restrict__ vrest_g)
{
    int n = blockIdx.x, h = blockIdx.y, d = threadIdx.x;
    float vall = 0.f, vgall = 0.f;
    for (int n2 = 0; n2 < NW; ++n2) {
        vall += vwin[(n2 * NH + h) * HD + d];
        vgall += vgwin[(n2 * NH + h) * HD + d];
    }
    float w  = vwin[(n * NH + h) * HD + d];
    float gw = vgwin[(n * NH + h) * HD + d];
    vrest_ng[(n * NH + h) * HD + d] = vall - w;
    vrest_g[(n * NH + h) * HD + d]  = vall - w - (vgall - gw);
}

// ---------------- MFMA flash attention (bf16-hi output only) ----------------
__global__ __launch_bounds__(256) void attn_mfma_kernel(
    const ushort_t* __restrict__ qb, const ushort_t* __restrict__ kb,
    const ushort_t* __restrict__ vtb, const float* __restrict__ vfull,
    const float* __restrict__ vrest_ng, const float* __restrict__ vrest_g,
    ushort_t* __restrict__ ath)
{
    __shared__ __align__(16) ushort_t sK[128 * 64];    // [key][8 chunks of 8 d], xor-swizzled
    __shared__ __align__(16) ushort_t sVt[64 * 128];   // [d][16 chunks of 8 j], xor-swizzled
    __shared__ __align__(16) ushort_t sP[4][16 * 136]; // per-wave P, padded rows
    __shared__ float sPe[96];
    __shared__ float sAe[128];
    __shared__ float sLe[2];

    const int tid  = threadIdx.x;
    const int lane = tid & 63;
    const int w    = tid >> 6;
    const int quad = lane >> 4;
    const int lm   = lane & 15;
    const int tile = blockIdx.x;   // 0..7
    const int h    = blockIdx.y;
    const int n    = blockIdx.z;

    const size_t qrow = (size_t)(n * WIN + tile * 64 + w * 16 + lm);
    const bf16x8 aq0 = *(const bf16x8*)&qb[qrow * HID + h * HD + quad * 8];
    const bf16x8 aq1 = *(const bf16x8*)&qb[qrow * HID + h * HD + 32 + quad * 8];

    f32x4 acc[4];
#pragma unroll
    for (int dt = 0; dt < 4; ++dt) acc[dt] = {0.f, 0.f, 0.f, 0.f};
    float lac[4] = {0.f, 0.f, 0.f, 0.f};
    bool qg[4];
#pragma unroll
    for (int r = 0; r < 4; ++r)
        qg[r] = (((tile * 64 + w * 16 + quad * 4 + r) & (GSTRIDE - 1)) == 0);

    ushort_t* sPw = sP[w];

    for (int c = 0; c < 4; ++c) {
        __syncthreads();
#pragma unroll
        for (int t = 0; t < 4; ++t) {
            int c2 = tid + t * 256;
            {
                int key = c2 >> 3, ck = c2 & 7, gc = ck ^ (key & 7);
                async16(&kb[(size_t)(n * WIN + c * 128 + key) * HID + h * HD + gc * 8],
                        &sK[c2 * 8]);
            }
            {
                int d = c2 >> 4, sl = c2 & 15, gj = sl ^ (d & 15);
                async16(&vtb[((size_t)(n * NH + h) * HD + d) * WIN + c * 128 + gj * 8],
                        &sVt[c2 * 8]);
            }
        }
        asm volatile("s_waitcnt vmcnt(0)" ::: "memory");
        __syncthreads();

        // ---- QK^T + softmax numerators ----
#pragma unroll
        for (int jt = 0; jt < 8; ++jt) {
            int key = jt * 16 + lm;
            bf16x8 bk0 = *(const bf16x8*)&sK[key * 64 + ((quad) ^ (key & 7)) * 8];
            bf16x8 bk1 = *(const bf16x8*)&sK[key * 64 + ((4 + quad) ^ (key & 7)) * 8];
            f32x4 s = {0.f, 0.f, 0.f, 0.f};
            s = __builtin_amdgcn_mfma_f32_16x16x32_bf16(aq0, bk0, s, 0, 0, 0);
            s = __builtin_amdgcn_mfma_f32_16x16x32_bf16(aq1, bk1, s, 0, 0, 0);
            const bool jg = (lm == 0) && ((jt & 1) == 0);   // key % 32 == 0
#pragma unroll
            for (int r = 0; r < 4; ++r) {
                float sv = s[r] * SCALE;
                if (qg[r] && jg) sv += sv;
                float p = __expf(sv);
                ushort_t ph = f32_to_bf16_rne(p);
                lac[r] += bf16_to_f32(ph);
                sPw[(quad * 4 + r) * 136 + jt * 16 + lm] = ph;
            }
        }

        // ---- PV ----
        bf16x8 pf[4];
#pragma unroll
        for (int jc = 0; jc < 4; ++jc)
            pf[jc] = *(const bf16x8*)&sPw[lm * 136 + jc * 32 + quad * 8];
#pragma unroll
        for (int dt = 0; dt < 4; ++dt) {
            int d = dt * 16 + lm;
#pragma unroll
            for (int jc = 0; jc < 4; ++jc) {
                bf16x8 vf = *(const bf16x8*)&sVt[d * 128 + (((jc * 4 + quad) ^ (d & 15))) * 8];
                acc[dt] = __builtin_amdgcn_mfma_f32_16x16x32_bf16(pf[jc], vf, acc[dt], 0, 0, 0);
            }
        }
    }

#pragma unroll
    for (int r = 0; r < 4; ++r) {
        float l = lac[r];
        l += __shfl_xor(l, 1);
        l += __shfl_xor(l, 2);
        l += __shfl_xor(l, 4);
        l += __shfl_xor(l, 8);
        lac[r] = l;
    }

    // ---- out-of-window global keys for the 2 global queries of this block ----
    __syncthreads();
    if (tid < 96) {
        int gq = tid / 48, kk = tid - gq * 48;
        int g = kk + (kk >= n * 16 ? 16 : 0);
        const ushort_t* qr = &qb[(size_t)(n * WIN + tile * 64 + gq * 32) * HID + h * HD];
        const ushort_t* kr = &kb[(size_t)(g * GSTRIDE) * HID + h * HD];
        float dot = 0.f;
#pragma unroll
        for (int dc = 0; dc < 8; ++dc) {
            bf16x8 qv = *(const bf16x8*)&qr[dc * 8];
            bf16x8 kv = *(const bf16x8*)&kr[dc * 8];
#pragma unroll
            for (int e = 0; e < 8; ++e) dot += (float)qv[e] * (float)kv[e];
        }
        sPe[tid] = __expf(dot * SCALE);
    }
    __syncthreads();
    if (tid < 128) {
        int gq = tid >> 6, d = tid & 63;
        float a = 0.f;
        for (int kk = 0; kk < 48; ++kk) {
            int g = kk + (kk >= n * 16 ? 16 : 0);
            a += sPe[gq * 48 + kk] * vfull[(size_t)(g * GSTRIDE) * HID + h * HD + d];
        }
        sAe[tid] = a;
    } else if (tid < 130) {
        int gq = tid - 128;
        float s = 0.f;
        for (int kk = 0; kk < 48; ++kk) s += sPe[gq * 48 + kk];
        sLe[gq] = s;
    }
    __syncthreads();

    // ---- epilogue: fold zero-score keys, normalize, write bf16 ----
    const float* vr_ng = &vrest_ng[(size_t)(n * NH + h) * HD];
    const float* vr_g  = &vrest_g[(size_t)(n * NH + h) * HD];
#pragma unroll
    for (int r = 0; r < 4; ++r) {
        int qo = w * 16 + quad * 4 + r;
        int qwin = tile * 64 + qo;
        bool isg = ((qwin & (GSTRIDE - 1)) == 0);
        int gq = (qo >> 5) & 1;
        float l = lac[r] + (float)(S_LEN - WIN);
        if (isg) l += sLe[gq] - 48.0f;
        float invl = 1.f / l;
        size_t row = (size_t)(n * WIN + qwin) * HID + h * HD;
#pragma unroll
        for (int dt = 0; dt < 4; ++dt) {
            int d = dt * 16 + lm;
            float o = acc[dt][r] + (isg ? (vr_g[d] + sAe[gq * 64 + d]) : vr_ng[d]);
            ath[row + d] = f32_to_bf16_rne(o * invl);
        }
    }
}

extern "C" void kernel_launch(void* const* d_in, const int* in_sizes, int n_in,
                              void* d_out, int out_size, void* d_ws, size_t ws_size,
                              hipStream_t stream) {
    const float* x   = (const float*)d_in[0];
    const float* wq  = (const float*)d_in[1];
    const float* bq  = (const float*)d_in[2];
    const float* wk  = (const float*)d_in[3];
    const float* bk_ = (const float*)d_in[4];
    const float* wv  = (const float*)d_in[5];
    const float* bv  = (const float*)d_in[6];
    const float* wo  = (const float*)d_in[7];
    const float* bo  = (const float*)d_in[8];
    float* out = (float*)d_out;

    const size_t M2 = 2u * 1024 * 1024, M1 = 1024 * 1024;
    float* ws = (float*)d_ws;
    float* vbuf     = ws;                    // 8 MB fp32 v
    float* part     = ws + M2;               // 16 MB: 2 x fp32 out-proj partials
    float* vwin     = ws + 3 * M2;
    float* vgwin    = vwin + NW * NH * HD;
    float* vrest_ng = vgwin + NW * NH * HD;
    float* vrest_g  = vrest_ng + NW * NH * HD;
    ushort_t* us = (ushort_t*)(ws + 3 * M2 + 16384);
    ushort_t* xb  = us;            // 4 MB
    ushort_t* wqb = xb + M2;       ushort_t* wkb = wqb + M1;
    ushort_t* wvb = wkb + M1;      ushort_t* wob = wvb + M1;
    ushort_t* qb  = wob + M1;      // 4 MB
    ushort_t* kb  = qb + M2;       // 4 MB
    ushort_t* vtb = kb + M2;       // 4 MB
    ushort_t* ath = vtb + M2;      // 4 MB

    CastJobs jobs;
    jobs.in[0] = x;  jobs.hi[0] = xb;  jobs.n4[0] = (int)(M2 / 4);
    jobs.in[1] = wq; jobs.hi[1] = wqb; jobs.n4[1] = (int)(M1 / 4);
    jobs.in[2] = wk; jobs.hi[2] = wkb; jobs.n4[2] = (int)(M1 / 4);
    jobs.in[3] = wv; jobs.hi[3] = wvb; jobs.n4[3] = (int)(M1 / 4);
    jobs.in[4] = wo; jobs.hi[4] = wob; jobs.n4[4] = (int)(M1 / 4);
    cast_all_kernel<<<dim3(2048, 5), 256, 0, stream>>>(jobs);

    // fused QKV: 128x64 blocks, grid (3 segs x 16 cols) x 16 rows = 768 blocks (3/CU)
    gemm_qkv_kernel<<<dim3(48, 16), 128, 0, stream>>>(
        xb, wqb, bq, wkb, bk_, wvb, bv, qb, kb, vbuf, vtb);

    vsum_kernel<<<dim3(NW, NH), 64, 0, stream>>>(vbuf, vwin, vgwin);
    vrest_kernel<<<dim3(NW, NH), 64, 0, stream>>>(vwin, vgwin, vrest_ng, vrest_g);

    attn_mfma_kernel<<<dim3(8, NH, NW), 256, 0, stream>>>(
        qb, kb, vtb, vbuf, vrest_ng, vrest_g, ath);

    // out projection: 128x64 blocks, K-split-2 -> 512 blocks (2/CU), then reduce+bias
    gemm_out_kernel<<<dim3(16, 16, 2), 128, 0, stream>>>(ath, wob, part);
    reduce_bias_kernel<<<2048, 256, 0, stream>>>(part, bo, out, (int)(M2 / 4));
}

// Round 6
// 158.219 us; speedup vs baseline: 5.2201x; 1.1990x over previous
//
#include <hip/hip_runtime.h>
#include <hip/hip_bf16.h>

#define S_LEN   2048
#define HID     1024
#define NH      16
#define HD      64
#define WIN     512
#define NW      4
#define NG      64
#define GSTRIDE 32
#define SCALE   0.125f   // 64^-0.5

typedef __bf16 bf16x8 __attribute__((ext_vector_type(8)));
typedef float  f32x4  __attribute__((ext_vector_type(4)));
typedef unsigned short ushort_t;

// ---------------- fp32 -> bf16 helpers ----------------
__device__ __forceinline__ ushort_t f32_to_bf16_rne(float f) {
    unsigned int u = __float_as_uint(f);
    u = u + 0x7FFFu + ((u >> 16) & 1u);
    return (ushort_t)(u >> 16);
}
__device__ __forceinline__ float bf16_to_f32(ushort_t h) {
    return __uint_as_float(((unsigned int)h) << 16);
}

// ---------------- batched cast: 5 tensors fp32 -> bf16 in one launch ----------------
struct CastJobs {
    const float* in[5];
    ushort_t* hi[5];
    int n4[5];
};

__global__ __launch_bounds__(256) void cast_all_kernel(CastJobs jobs) {
    int j = blockIdx.y;
    int i = blockIdx.x * 256 + threadIdx.x;
    if (i >= jobs.n4[j]) return;
    float4 f = ((const float4*)jobs.in[j])[i];
    ushort4 h;
    h.x = f32_to_bf16_rne(f.x);
    h.y = f32_to_bf16_rne(f.y);
    h.z = f32_to_bf16_rne(f.z);
    h.w = f32_to_bf16_rne(f.w);
    ((ushort4*)jobs.hi[j])[i] = h;
}

// ---------------- async global -> LDS (16B per lane) ----------------
__device__ __forceinline__ void async16(const ushort_t* g, ushort_t* l) {
    __builtin_amdgcn_global_load_lds(
        (const __attribute__((address_space(1))) void*)g,
        (__attribute__((address_space(3))) void*)l, 16, 0, 0);
}

// ============== single-bf16 MFMA GEMM, 128x64 block, 2 waves ==============
// Wave w computes a full 64x64 tile (FI=FJ=4): 16 MFMA per 8 ds_read_b128
// per BK=32 step -> 32 FLOP/LDS-byte. XOR swizzle on the GLOBAL chunk index
// keeps frag reads conflict-free while staying global_load_lds-compatible.

// --- QKV variant: 3 weight segments; bf16 q/k outputs + transposed bf16 V ---
__global__ __launch_bounds__(128) void gemm_qkv_kernel(
    const ushort_t* __restrict__ xb,
    const ushort_t* __restrict__ wqb, const float* __restrict__ bq,
    const ushort_t* __restrict__ wkb, const float* __restrict__ bk,
    const ushort_t* __restrict__ wvb, const float* __restrict__ bv,
    ushort_t* __restrict__ qb, ushort_t* __restrict__ kb,
    ushort_t* __restrict__ vtb)
{
    __shared__ ushort_t sA[128 * 32];
    __shared__ ushort_t sB[64 * 32];
    const int tid  = threadIdx.x;
    const int lane = tid & 63;
    const int w    = tid >> 6;
    const int quad = lane >> 4, lm = lane & 15;
    const int seg  = blockIdx.x >> 4;
    const int bn   = (blockIdx.x & 15) * 64;
    const int bm   = blockIdx.y * 128;

    const ushort_t* B  = (seg == 0) ? wqb : (seg == 1) ? wkb : wvb;
    const float* bias  = (seg == 0) ? bq  : (seg == 1) ? bk  : bv;

    f32x4 acc[4][4];
#pragma unroll
    for (int i = 0; i < 4; ++i)
#pragma unroll
        for (int j = 0; j < 4; ++j) acc[i][j] = {0.f, 0.f, 0.f, 0.f};

    for (int k0 = 0; k0 < HID; k0 += 32) {
        __syncthreads();
#pragma unroll
        for (int t = 0; t < 4; ++t) {          // A: 512 chunks, 4/thread
            int c = tid + t * 128;
            int row = c >> 2, kp = c & 3, gc = kp ^ ((row >> 1) & 3);
            async16(&xb[(size_t)(bm + row) * HID + k0 + gc * 8], &sA[c * 8]);
        }
#pragma unroll
        for (int t = 0; t < 2; ++t) {          // B: 256 chunks, 2/thread
            int c = tid + t * 128;
            int row = c >> 2, kp = c & 3, gc = kp ^ ((row >> 1) & 3);
            async16(&B[(size_t)(bn + row) * HID + k0 + gc * 8], &sB[c * 8]);
        }
        asm volatile("s_waitcnt vmcnt(0)" ::: "memory");
        __syncthreads();

        bf16x8 af[4], bf[4];
#pragma unroll
        for (int i = 0; i < 4; ++i) {
            int row = w * 64 + i * 16 + lm;
            int slot = quad ^ ((row >> 1) & 3);
            af[i] = *(const bf16x8*)&sA[row * 32 + slot * 8];
        }
#pragma unroll
        for (int j = 0; j < 4; ++j) {
            int row = j * 16 + lm;
            int slot = quad ^ ((row >> 1) & 3);
            bf[j] = *(const bf16x8*)&sB[row * 32 + slot * 8];
        }
#pragma unroll
        for (int i = 0; i < 4; ++i)
#pragma unroll
            for (int j = 0; j < 4; ++j)
                acc[i][j] = __builtin_amdgcn_mfma_f32_16x16x32_bf16(af[i], bf[j], acc[i][j], 0, 0, 0);
    }

    // epilogue: C/D layout col=lane&15, row=quad*4+reg
#pragma unroll
    for (int i = 0; i < 4; ++i)
#pragma unroll
        for (int j = 0; j < 4; ++j) {
            int col = bn + j * 16 + lm;
            float b = bias[col];
#pragma unroll
            for (int r = 0; r < 4; ++r) {
                int row = bm + w * 64 + i * 16 + quad * 4 + r;
                float val = acc[i][j][r] + b;
                if (seg == 0) {
                    qb[(size_t)row * HID + col] = f32_to_bf16_rne(val);
                } else if (seg == 1) {
                    kb[(size_t)row * HID + col] = f32_to_bf16_rne(val);
                } else {
                    int hh = col >> 6, dd = col & 63, nn = row >> 9, jj = row & 511;
                    vtb[(((size_t)nn * NH + hh) * HD + dd) * WIN + jj] = f32_to_bf16_rne(val);
                }
            }
        }
}

// --- out-proj: direct 64x64 x K=1024 with fused bias, fp32 out ---
__global__ __launch_bounds__(128) void gemm_out_kernel(
    const ushort_t* __restrict__ A, const ushort_t* __restrict__ B,
    const float* __restrict__ bias, float* __restrict__ out)
{
    __shared__ ushort_t sA[64 * 32];
    __shared__ ushort_t sB[64 * 32];
    const int tid  = threadIdx.x;
    const int lane = tid & 63;
    const int w    = tid >> 6;
    const int quad = lane >> 4, lm = lane & 15;
    const int bn   = blockIdx.x * 64;
    const int bm   = blockIdx.y * 64;

    f32x4 acc[2][4];   // wave tile 32x64: FI=2, FJ=4
#pragma unroll
    for (int i = 0; i < 2; ++i)
#pragma unroll
        for (int j = 0; j < 4; ++j) acc[i][j] = {0.f, 0.f, 0.f, 0.f};

    for (int k0 = 0; k0 < HID; k0 += 32) {
        __syncthreads();
#pragma unroll
        for (int t = 0; t < 2; ++t) {          // A: 256 chunks, 2/thread
            int c = tid + t * 128;
            int row = c >> 2, kp = c & 3, gc = kp ^ ((row >> 1) & 3);
            async16(&A[(size_t)(bm + row) * HID + k0 + gc * 8], &sA[c * 8]);
        }
#pragma unroll
        for (int t = 0; t < 2; ++t) {          // B: 256 chunks, 2/thread
            int c = tid + t * 128;
            int row = c >> 2, kp = c & 3, gc = kp ^ ((row >> 1) & 3);
            async16(&B[(size_t)(bn + row) * HID + k0 + gc * 8], &sB[c * 8]);
        }
        asm volatile("s_waitcnt vmcnt(0)" ::: "memory");
        __syncthreads();

        bf16x8 af[2], bf[4];
#pragma unroll
        for (int i = 0; i < 2; ++i) {
            int row = w * 32 + i * 16 + lm;
            int slot = quad ^ ((row >> 1) & 3);
            af[i] = *(const bf16x8*)&sA[row * 32 + slot * 8];
        }
#pragma unroll
        for (int j = 0; j < 4; ++j) {
            int row = j * 16 + lm;
            int slot = quad ^ ((row >> 1) & 3);
            bf[j] = *(const bf16x8*)&sB[row * 32 + slot * 8];
        }
#pragma unroll
        for (int i = 0; i < 2; ++i)
#pragma unroll
            for (int j = 0; j < 4; ++j)
                acc[i][j] = __builtin_amdgcn_mfma_f32_16x16x32_bf16(af[i], bf[j], acc[i][j], 0, 0, 0);
    }

#pragma unroll
    for (int i = 0; i < 2; ++i)
#pragma unroll
        for (int j = 0; j < 4; ++j) {
            int col = bn + j * 16 + lm;
            float b = bias[col];
#pragma unroll
            for (int r = 0; r < 4; ++r) {
                int row = bm + w * 32 + i * 16 + quad * 4 + r;
                out[(size_t)row * HID + col] = acc[i][j][r] + b;
            }
        }
}

// ---------------- V sums from transposed bf16 V: wave per (n,h,d) row ----------------
__global__ __launch_bounds__(256) void vsum_kernel(const ushort_t* __restrict__ vtb,
    float* __restrict__ vwin, float* __restrict__ vgwin)
{
    int wid  = blockIdx.x * 4 + (threadIdx.x >> 6);   // 0..4095 = (n*NH+h)*HD+d
    int lane = threadIdx.x & 63;
    bf16x8 v = *(const bf16x8*)&vtb[(size_t)wid * WIN + lane * 8];
    float s = 0.f;
#pragma unroll
    for (int e = 0; e < 8; ++e) s += (float)v[e];
    float sg = ((lane & 3) == 0) ? (float)v[0] : 0.f;  // j = lane*8, j%32==0 iff lane%4==0
#pragma unroll
    for (int off = 1; off < 64; off <<= 1) {
        s  += __shfl_xor(s,  off);
        sg += __shfl_xor(sg, off);
    }
    if (lane == 0) { vwin[wid] = s; vgwin[wid] = sg; }
}

// ---------------- MFMA flash attention (vrest folded into epilogue) ----------------
__global__ __launch_bounds__(256) void attn_mfma_kernel(
    const ushort_t* __restrict__ qb, const ushort_t* __restrict__ kb,
    const ushort_t* __restrict__ vtb,
    const float* __restrict__ vwin, const float* __restrict__ vgwin,
    ushort_t* __restrict__ ath)
{
    __shared__ __align__(16) ushort_t sK[128 * 64];    // [key][8 chunks of 8 d], xor-swizzled
    __shared__ __align__(16) ushort_t sVt[64 * 128];   // [d][16 chunks of 8 j], xor-swizzled
    __shared__ __align__(16) ushort_t sP[4][16 * 136]; // per-wave P, padded rows
    __shared__ float sPe[96];
    __shared__ float sAe[128];
    __shared__ float sLe[2];

    const int tid  = threadIdx.x;
    const int lane = tid & 63;
    const int w    = tid >> 6;
    const int quad = lane >> 4;
    const int lm   = lane & 15;
    const int tile = blockIdx.x;   // 0..7
    const int h    = blockIdx.y;
    const int n    = blockIdx.z;

    const size_t qrow = (size_t)(n * WIN + tile * 64 + w * 16 + lm);
    const bf16x8 aq0 = *(const bf16x8*)&qb[qrow * HID + h * HD + quad * 8];
    const bf16x8 aq1 = *(const bf16x8*)&qb[qrow * HID + h * HD + 32 + quad * 8];

    f32x4 acc[4];
#pragma unroll
    for (int dt = 0; dt < 4; ++dt) acc[dt] = {0.f, 0.f, 0.f, 0.f};
    float lac[4] = {0.f, 0.f, 0.f, 0.f};
    bool qg[4];
#pragma unroll
    for (int r = 0; r < 4; ++r)
        qg[r] = (((tile * 64 + w * 16 + quad * 4 + r) & (GSTRIDE - 1)) == 0);

    ushort_t* sPw = sP[w];

    for (int c = 0; c < 4; ++c) {
        __syncthreads();
#pragma unroll
        for (int t = 0; t < 4; ++t) {
            int c2 = tid + t * 256;
            {
                int key = c2 >> 3, ck = c2 & 7, gc = ck ^ (key & 7);
                async16(&kb[(size_t)(n * WIN + c * 128 + key) * HID + h * HD + gc * 8],
                        &sK[c2 * 8]);
            }
            {
                int d = c2 >> 4, sl = c2 & 15, gj = sl ^ (d & 15);
                async16(&vtb[((size_t)(n * NH + h) * HD + d) * WIN + c * 128 + gj * 8],
                        &sVt[c2 * 8]);
            }
        }
        asm volatile("s_waitcnt vmcnt(0)" ::: "memory");
        __syncthreads();

        // ---- QK^T + softmax numerators ----
#pragma unroll
        for (int jt = 0; jt < 8; ++jt) {
            int key = jt * 16 + lm;
            bf16x8 bk0 = *(const bf16x8*)&sK[key * 64 + ((quad) ^ (key & 7)) * 8];
            bf16x8 bk1 = *(const bf16x8*)&sK[key * 64 + ((4 + quad) ^ (key & 7)) * 8];
            f32x4 s = {0.f, 0.f, 0.f, 0.f};
            s = __builtin_amdgcn_mfma_f32_16x16x32_bf16(aq0, bk0, s, 0, 0, 0);
            s = __builtin_amdgcn_mfma_f32_16x16x32_bf16(aq1, bk1, s, 0, 0, 0);
            const bool jg = (lm == 0) && ((jt & 1) == 0);   // key % 32 == 0
#pragma unroll
            for (int r = 0; r < 4; ++r) {
                float sv = s[r] * SCALE;
                if (qg[r] && jg) sv += sv;
                float p = __expf(sv);
                ushort_t ph = f32_to_bf16_rne(p);
                lac[r] += bf16_to_f32(ph);
                sPw[(quad * 4 + r) * 136 + jt * 16 + lm] = ph;
            }
        }

        // ---- PV ----
        bf16x8 pf[4];
#pragma unroll
        for (int jc = 0; jc < 4; ++jc)
            pf[jc] = *(const bf16x8*)&sPw[lm * 136 + jc * 32 + quad * 8];
#pragma unroll
        for (int dt = 0; dt < 4; ++dt) {
            int d = dt * 16 + lm;
#pragma unroll
            for (int jc = 0; jc < 4; ++jc) {
                bf16x8 vf = *(const bf16x8*)&sVt[d * 128 + (((jc * 4 + quad) ^ (d & 15))) * 8];
                acc[dt] = __builtin_amdgcn_mfma_f32_16x16x32_bf16(pf[jc], vf, acc[dt], 0, 0, 0);
            }
        }
    }

#pragma unroll
    for (int r = 0; r < 4; ++r) {
        float l = lac[r];
        l += __shfl_xor(l, 1);
        l += __shfl_xor(l, 2);
        l += __shfl_xor(l, 4);
        l += __shfl_xor(l, 8);
        lac[r] = l;
    }

    // ---- out-of-window global keys for the 2 global queries of this block ----
    __syncthreads();
    if (tid < 96) {
        int gq = tid / 48, kk = tid - gq * 48;
        int g = kk + (kk >= n * 16 ? 16 : 0);
        const ushort_t* qr = &qb[(size_t)(n * WIN + tile * 64 + gq * 32) * HID + h * HD];
        const ushort_t* kr = &kb[(size_t)(g * GSTRIDE) * HID + h * HD];
        float dot = 0.f;
#pragma unroll
        for (int dc = 0; dc < 8; ++dc) {
            bf16x8 qv = *(const bf16x8*)&qr[dc * 8];
            bf16x8 kv = *(const bf16x8*)&kr[dc * 8];
#pragma unroll
            for (int e = 0; e < 8; ++e) dot += (float)qv[e] * (float)kv[e];
        }
        sPe[tid] = __expf(dot * SCALE);
    }
    __syncthreads();
    if (tid < 128) {
        int gq = tid >> 6, d = tid & 63;
        float a = 0.f;
        for (int kk = 0; kk < 48; ++kk) {
            int g = kk + (kk >= n * 16 ? 16 : 0);
            int gwin = g >> 4, jj = (g & 15) * GSTRIDE;
            a += sPe[gq * 48 + kk] *
                 bf16_to_f32(vtb[((size_t)(gwin * NH + h) * HD + d) * WIN + jj]);
        }
        sAe[tid] = a;
    } else if (tid < 130) {
        int gq = tid - 128;
        float s = 0.f;
        for (int kk = 0; kk < 48; ++kk) s += sPe[gq * 48 + kk];
        sLe[gq] = s;
    }
    __syncthreads();

    // ---- vrest inline from the vwin/vgwin tables (16 KB, L1-hot) ----
    float vr_ng_r[4], vr_g_r[4];
#pragma unroll
    for (int dt = 0; dt < 4; ++dt) {
        int d = dt * 16 + lm;
        float vall = 0.f, vgall = 0.f;
#pragma unroll
        for (int n2 = 0; n2 < NW; ++n2) {
            vall  += vwin [(n2 * NH + h) * HD + d];
            vgall += vgwin[(n2 * NH + h) * HD + d];
        }
        float w_  = vwin [(n * NH + h) * HD + d];
        float gw_ = vgwin[(n * NH + h) * HD + d];
        vr_ng_r[dt] = vall - w_;
        vr_g_r[dt]  = vall - w_ - (vgall - gw_);
    }

    // ---- epilogue: fold zero-score keys, normalize, write bf16 ----
#pragma unroll
    for (int r = 0; r < 4; ++r) {
        int qo = w * 16 + quad * 4 + r;
        int qwin = tile * 64 + qo;
        bool isg = ((qwin & (GSTRIDE - 1)) == 0);
        int gq = (qo >> 5) & 1;
        float l = lac[r] + (float)(S_LEN - WIN);
        if (isg) l += sLe[gq] - 48.0f;
        float invl = 1.f / l;
        size_t row = (size_t)(n * WIN + qwin) * HID + h * HD;
#pragma unroll
        for (int dt = 0; dt < 4; ++dt) {
            int d = dt * 16 + lm;
            float o = acc[dt][r] + (isg ? (vr_g_r[dt] + sAe[gq * 64 + d]) : vr_ng_r[dt]);
            ath[row + d] = f32_to_bf16_rne(o * invl);
        }
    }
}

extern "C" void kernel_launch(void* const* d_in, const int* in_sizes, int n_in,
                              void* d_out, int out_size, void* d_ws, size_t ws_size,
                              hipStream_t stream) {
    const float* x   = (const float*)d_in[0];
    const float* wq  = (const float*)d_in[1];
    const float* bq  = (const float*)d_in[2];
    const float* wk  = (const float*)d_in[3];
    const float* bk_ = (const float*)d_in[4];
    const float* wv  = (const float*)d_in[5];
    const float* bv  = (const float*)d_in[6];
    const float* wo  = (const float*)d_in[7];
    const float* bo  = (const float*)d_in[8];
    float* out = (float*)d_out;

    const size_t M2 = 2u * 1024 * 1024, M1 = 1024 * 1024;
    float* ws = (float*)d_ws;
    float* vwin  = ws;                       // 4096 floats
    float* vgwin = vwin + NW * NH * HD;      // 4096 floats
    ushort_t* us = (ushort_t*)(ws + 16384);
    ushort_t* xb  = us;            // 4 MB
    ushort_t* wqb = xb + M2;       ushort_t* wkb = wqb + M1;
    ushort_t* wvb = wkb + M1;      ushort_t* wob = wvb + M1;
    ushort_t* qb  = wob + M1;      // 4 MB
    ushort_t* kb  = qb + M2;       // 4 MB
    ushort_t* vtb = kb + M2;       // 4 MB
    ushort_t* ath = vtb + M2;      // 4 MB

    CastJobs jobs;
    jobs.in[0] = x;  jobs.hi[0] = xb;  jobs.n4[0] = (int)(M2 / 4);
    jobs.in[1] = wq; jobs.hi[1] = wqb; jobs.n4[1] = (int)(M1 / 4);
    jobs.in[2] = wk; jobs.hi[2] = wkb; jobs.n4[2] = (int)(M1 / 4);
    jobs.in[3] = wv; jobs.hi[3] = wvb; jobs.n4[3] = (int)(M1 / 4);
    jobs.in[4] = wo; jobs.hi[4] = wob; jobs.n4[4] = (int)(M1 / 4);
    cast_all_kernel<<<dim3(2048, 5), 256, 0, stream>>>(jobs);

    // fused QKV: 128x64 blocks, grid (3 segs x 16 cols) x 16 rows = 768 blocks (3/CU)
    gemm_qkv_kernel<<<dim3(48, 16), 128, 0, stream>>>(
        xb, wqb, bq, wkb, bk_, wvb, bv, qb, kb, vtb);

    // V sums from vtb: 4096 waves, one per (n,h,d) row
    vsum_kernel<<<1024, 256, 0, stream>>>(vtb, vwin, vgwin);

    attn_mfma_kernel<<<dim3(8, NH, NW), 256, 0, stream>>>(
        qb, kb, vtb, vwin, vgwin, ath);

    // out projection: direct 64x64 x K=1024 + fused bias, 512 blocks (2/CU)
    gemm_out_kernel<<<dim3(16, 32), 128, 0, stream>>>(ath, wob, bo, out);
}